// Round 1
// baseline (519.551 us; speedup 1.0000x reference)
//
#include <hip/hip_runtime.h>
#include <hip/hip_bf16.h>
#include <cstdint>

#define NB 8          // nodes per block in embed kernel
#define NEG 0.2f

// ---- monotone float<->uint mapping for atomicMax on floats ----
__device__ __forceinline__ unsigned f2ord(float f){
  unsigned b = __float_as_uint(f);
  return (b & 0x80000000u) ? ~b : (b | 0x80000000u);
}
__device__ __forceinline__ float ord2f(unsigned u){
  unsigned b = (u & 0x80000000u) ? (u ^ 0x80000000u) : ~u;
  return __uint_as_float(b);
}

// ---- kernel 1: h = x@emb_w + emb_b ; xh = h@gat_w ; a_src/a_dst dots ----
__global__ __launch_bounds__(128)
void node_embed_kernel(const float* __restrict__ x, const float* __restrict__ emb_w,
                       const float* __restrict__ emb_b, const float* __restrict__ gat_w,
                       const float* __restrict__ att_src, const float* __restrict__ att_dst,
                       float* __restrict__ h_out, float* __restrict__ xh,
                       float* __restrict__ a_s, float* __restrict__ a_d, int nN)
{
  __shared__ __align__(16) float hs[NB][128];
  __shared__ float xs[NB][12];
  int t = threadIdx.x;               // 0..127
  int n0 = blockIdx.x * NB;

  if (t < NB*9){
    int j = t/9, k = t - j*9;
    int n = n0 + j;
    xs[j][k] = (n < nN) ? x[(size_t)n*9 + k] : 0.f;
  }
  __syncthreads();

  float bb = emb_b[t];
  #pragma unroll
  for (int j=0;j<NB;j++){
    float acc = bb;
    #pragma unroll
    for (int k=0;k<9;k++) acc += xs[j][k]*emb_w[k*128+t];
    hs[j][t] = acc;
    int n = n0 + j;
    if (n < nN) h_out[(size_t)n*128 + t] = acc;
  }
  __syncthreads();

  float acc0[NB], acc1[NB], acc2[NB];
  #pragma unroll
  for (int j=0;j<NB;j++){ acc0[j]=0.f; acc1[j]=0.f; acc2[j]=0.f; }

  for (int k=0;k<128;k+=4){
    float w0[4], w1[4], w2[4];
    #pragma unroll
    for (int kk=0;kk<4;kk++){
      w0[kk] = gat_w[(k+kk)*384 + t      ];
      w1[kk] = gat_w[(k+kk)*384 + t + 128];
      w2[kk] = gat_w[(k+kk)*384 + t + 256];
    }
    #pragma unroll
    for (int j=0;j<NB;j++){
      float4 hv = *(const float4*)&hs[j][k];
      acc0[j] += hv.x*w0[0] + hv.y*w0[1] + hv.z*w0[2] + hv.w*w0[3];
      acc1[j] += hv.x*w1[0] + hv.y*w1[1] + hv.z*w1[2] + hv.w*w1[3];
      acc2[j] += hv.x*w2[0] + hv.y*w2[1] + hv.z*w2[2] + hv.w*w2[3];
    }
  }

  #pragma unroll
  for (int j=0;j<NB;j++){
    int n = n0 + j;
    if (n < nN){
      size_t base = (size_t)n*384 + t;
      xh[base      ] = acc0[j];
      xh[base + 128] = acc1[j];
      xh[base + 256] = acc2[j];
    }
  }

  // attention dot products: a_src[n][h] = sum_c xh[n][h][c]*att_src[h][c]
  float as0=att_src[t], as1=att_src[128+t], as2=att_src[256+t];
  float ad0=att_dst[t], ad1=att_dst[128+t], ad2=att_dst[256+t];
  __shared__ float red[2][NB][6];
  int wv = t>>6, ln = t&63;
  #pragma unroll
  for (int j=0;j<NB;j++){
    float pr[6] = {acc0[j]*as0, acc1[j]*as1, acc2[j]*as2,
                   acc0[j]*ad0, acc1[j]*ad1, acc2[j]*ad2};
    #pragma unroll
    for (int off=32; off; off>>=1){
      #pragma unroll
      for (int i=0;i<6;i++) pr[i] += __shfl_down(pr[i], off);
    }
    if (ln==0){
      #pragma unroll
      for (int i=0;i<6;i++) red[wv][j][i]=pr[i];
    }
  }
  __syncthreads();
  if (t < NB*6){
    int j=t/6, i=t-j*6;
    int n=n0+j;
    if (n<nN){
      float v = red[0][j][i]+red[1][j][i];
      if (i<3) a_s[(size_t)n*3+i]=v; else a_d[(size_t)n*3+(i-3)]=v;
    }
  }
}

// ---- kernel 2: per-edge leaky_relu(e) -> atomicMax of ordered-uint ----
__global__ __launch_bounds__(256)
void edge_max_kernel(const int* __restrict__ ei, const float* __restrict__ a_s,
                     const float* __restrict__ a_d, unsigned* __restrict__ emax,
                     int nE, int nN)
{
  int e = blockIdx.x*blockDim.x + threadIdx.x;
  int tot = nE + nN;
  if (e >= tot) return;
  int s, d;
  if (e < nE){ s = ei[e]; d = ei[nE + e]; } else { s = d = e - nE; }
  #pragma unroll
  for (int h=0;h<3;h++){
    float v = a_s[(size_t)s*3+h] + a_d[(size_t)d*3+h];
    v = v > 0.f ? v : NEG*v;
    atomicMax(&emax[(size_t)d*3+h], f2ord(v));
  }
}

// ---- kernel 3: denom = segment_sum(exp(e - emax[dst])) ----
__global__ __launch_bounds__(256)
void edge_sum_kernel(const int* __restrict__ ei, const float* __restrict__ a_s,
                     const float* __restrict__ a_d, const unsigned* __restrict__ emax,
                     float* __restrict__ denom, int nE, int nN)
{
  int e = blockIdx.x*blockDim.x + threadIdx.x;
  int tot = nE + nN;
  if (e >= tot) return;
  int s, d;
  if (e < nE){ s = ei[e]; d = ei[nE + e]; } else { s = d = e - nE; }
  #pragma unroll
  for (int h=0;h<3;h++){
    float v = a_s[(size_t)s*3+h] + a_d[(size_t)d*3+h];
    v = v > 0.f ? v : NEG*v;
    float m = ord2f(emax[(size_t)d*3+h]);
    unsafeAtomicAdd(&denom[(size_t)d*3+h], __expf(v - m));
  }
}

// ---- kernel 4: message pass, one wave per edge, head-mean folded in ----
__global__ __launch_bounds__(256)
void edge_msg_kernel(const int* __restrict__ ei, const float* __restrict__ a_s,
                     const float* __restrict__ a_d, const unsigned* __restrict__ emax,
                     const float* __restrict__ denom, const float* __restrict__ xh,
                     float* __restrict__ accO, int nE, int nN)
{
  int gid = blockIdx.x*blockDim.x + threadIdx.x;
  int w = gid >> 6;
  int lane = gid & 63;
  int tot = nE + nN;
  if (w >= tot) return;
  int s, d;
  if (w < nE){ s = ei[w]; d = ei[nE + w]; } else { s = d = w - nE; }

  float alpha[3];
  #pragma unroll
  for (int h=0;h<3;h++){
    float v = a_s[(size_t)s*3+h] + a_d[(size_t)d*3+h];
    v = v > 0.f ? v : NEG*v;
    float m = ord2f(emax[(size_t)d*3+h]);
    alpha[h] = __expf(v - m) / (denom[(size_t)d*3+h] + 1e-16f);
  }

  const float* xs = xh + (size_t)s*384;
  float* ad = accO + (size_t)d*128;
  #pragma unroll
  for (int half=0; half<2; half++){
    int c = lane + half*64;
    float msg = alpha[0]*xs[c] + alpha[1]*xs[128+c] + alpha[2]*xs[256+c];
    unsafeAtomicAdd(&ad[c], msg);
  }
}

// ---- kernel 5: out = ((acc/3 + bias + h) @ out_w) + out_b, wave per node ----
__global__ __launch_bounds__(256)
void out_kernel(const float* __restrict__ accO, const float* __restrict__ h,
                const float* __restrict__ gat_bias, const float* __restrict__ out_w,
                const float* __restrict__ out_b, float* __restrict__ out, int nN)
{
  int gid = blockIdx.x*blockDim.x + threadIdx.x;
  int n = gid >> 6;
  int lane = gid & 63;
  if (n >= nN) return;
  int c0 = lane, c1 = lane + 64;
  float v0 = accO[(size_t)n*128+c0]*(1.f/3.f) + gat_bias[c0] + h[(size_t)n*128+c0];
  float v1 = accO[(size_t)n*128+c1]*(1.f/3.f) + gat_bias[c1] + h[(size_t)n*128+c1];
  float p[4];
  #pragma unroll
  for (int j=0;j<4;j++) p[j] = v0*out_w[c0*4+j] + v1*out_w[c1*4+j];
  #pragma unroll
  for (int off=32; off; off>>=1){
    #pragma unroll
    for (int j=0;j<4;j++) p[j] += __shfl_down(p[j], off);
  }
  if (lane==0){
    #pragma unroll
    for (int j=0;j<4;j++) out[(size_t)n*4+j] = p[j] + out_b[j];
  }
}

extern "C" void kernel_launch(void* const* d_in, const int* in_sizes, int n_in,
                              void* d_out, int out_size, void* d_ws, size_t ws_size,
                              hipStream_t stream) {
  const float* x       = (const float*)d_in[0];
  const float* emb_w   = (const float*)d_in[1];
  const float* emb_b   = (const float*)d_in[2];
  const float* gat_w   = (const float*)d_in[3];
  const float* att_src = (const float*)d_in[4];
  const float* att_dst = (const float*)d_in[5];
  const float* gat_bias= (const float*)d_in[6];
  const float* out_w   = (const float*)d_in[7];
  const float* out_b   = (const float*)d_in[8];
  const int*   ei      = (const int*)d_in[9];
  float* out = (float*)d_out;

  int nN = in_sizes[0]/9;
  int nE = in_sizes[9]/2;

  char* p = (char*)d_ws;
  auto alloc = [&](size_t bytes)->char*{
    char* r = p; p += (bytes + 255) & ~(size_t)255; return r;
  };
  float*    h_buf = (float*)   alloc((size_t)nN*128*4);
  float*    xh    = (float*)   alloc((size_t)nN*384*4);
  float*    a_s   = (float*)   alloc((size_t)nN*3*4);
  float*    a_d   = (float*)   alloc((size_t)nN*3*4);
  unsigned* emax  = (unsigned*)alloc((size_t)nN*3*4);
  float*    denom = (float*)   alloc((size_t)nN*3*4);
  float*    accO  = (float*)   alloc((size_t)nN*128*4);

  hipMemsetAsync(emax,  0, (size_t)nN*3*4,   stream);
  hipMemsetAsync(denom, 0, (size_t)nN*3*4,   stream);
  hipMemsetAsync(accO,  0, (size_t)nN*128*4, stream);

  node_embed_kernel<<<(nN+NB-1)/NB, 128, 0, stream>>>(
      x, emb_w, emb_b, gat_w, att_src, att_dst, h_buf, xh, a_s, a_d, nN);

  int tot = nE + nN;
  edge_max_kernel<<<(tot+255)/256, 256, 0, stream>>>(ei, a_s, a_d, emax, nE, nN);
  edge_sum_kernel<<<(tot+255)/256, 256, 0, stream>>>(ei, a_s, a_d, emax, denom, nE, nN);
  edge_msg_kernel<<<((size_t)tot*64+255)/256, 256, 0, stream>>>(
      ei, a_s, a_d, emax, denom, xh, accO, nE, nN);
  out_kernel<<<((size_t)nN*64+255)/256, 256, 0, stream>>>(
      accO, h_buf, gat_bias, out_w, out_b, out, nN);
}

// Round 2
// 449.230 us; speedup vs baseline: 1.1565x; 1.1565x over previous
//
#include <hip/hip_runtime.h>
#include <hip/hip_bf16.h>
#include <cstdint>

#define NB 8          // nodes per block in embed kernel
#define NEG 0.2f
#define SCAN_T 1024

// ---- kernel 1: h = x@emb_w + emb_b ; xh = h@gat_w ; a_src/a_dst dots ----
__global__ __launch_bounds__(128)
void node_embed_kernel(const float* __restrict__ x, const float* __restrict__ emb_w,
                       const float* __restrict__ emb_b, const float* __restrict__ gat_w,
                       const float* __restrict__ att_src, const float* __restrict__ att_dst,
                       float* __restrict__ h_out, float* __restrict__ xh,
                       float* __restrict__ a_s, float* __restrict__ a_d, int nN)
{
  __shared__ __align__(16) float hs[NB][128];
  __shared__ float xs[NB][12];
  int t = threadIdx.x;               // 0..127
  int n0 = blockIdx.x * NB;

  if (t < NB*9){
    int j = t/9, k = t - j*9;
    int n = n0 + j;
    xs[j][k] = (n < nN) ? x[(size_t)n*9 + k] : 0.f;
  }
  __syncthreads();

  float bb = emb_b[t];
  #pragma unroll
  for (int j=0;j<NB;j++){
    float acc = bb;
    #pragma unroll
    for (int k=0;k<9;k++) acc += xs[j][k]*emb_w[k*128+t];
    hs[j][t] = acc;
    int n = n0 + j;
    if (n < nN) h_out[(size_t)n*128 + t] = acc;
  }
  __syncthreads();

  float acc0[NB], acc1[NB], acc2[NB];
  #pragma unroll
  for (int j=0;j<NB;j++){ acc0[j]=0.f; acc1[j]=0.f; acc2[j]=0.f; }

  for (int k=0;k<128;k+=4){
    float w0[4], w1[4], w2[4];
    #pragma unroll
    for (int kk=0;kk<4;kk++){
      w0[kk] = gat_w[(k+kk)*384 + t      ];
      w1[kk] = gat_w[(k+kk)*384 + t + 128];
      w2[kk] = gat_w[(k+kk)*384 + t + 256];
    }
    #pragma unroll
    for (int j=0;j<NB;j++){
      float4 hv = *(const float4*)&hs[j][k];
      acc0[j] += hv.x*w0[0] + hv.y*w0[1] + hv.z*w0[2] + hv.w*w0[3];
      acc1[j] += hv.x*w1[0] + hv.y*w1[1] + hv.z*w1[2] + hv.w*w1[3];
      acc2[j] += hv.x*w2[0] + hv.y*w2[1] + hv.z*w2[2] + hv.w*w2[3];
    }
  }

  #pragma unroll
  for (int j=0;j<NB;j++){
    int n = n0 + j;
    if (n < nN){
      size_t base = (size_t)n*384 + t;
      xh[base      ] = acc0[j];
      xh[base + 128] = acc1[j];
      xh[base + 256] = acc2[j];
    }
  }

  // attention dot products
  float as0=att_src[t], as1=att_src[128+t], as2=att_src[256+t];
  float ad0=att_dst[t], ad1=att_dst[128+t], ad2=att_dst[256+t];
  __shared__ float red[2][NB][6];
  int wv = t>>6, ln = t&63;
  #pragma unroll
  for (int j=0;j<NB;j++){
    float pr[6] = {acc0[j]*as0, acc1[j]*as1, acc2[j]*as2,
                   acc0[j]*ad0, acc1[j]*ad1, acc2[j]*ad2};
    #pragma unroll
    for (int off=32; off; off>>=1){
      #pragma unroll
      for (int i=0;i<6;i++) pr[i] += __shfl_down(pr[i], off);
    }
    if (ln==0){
      #pragma unroll
      for (int i=0;i<6;i++) red[wv][j][i]=pr[i];
    }
  }
  __syncthreads();
  if (t < NB*6){
    int j=t/6, i=t-j*6;
    int n=n0+j;
    if (n<nN){
      float v = red[0][j][i]+red[1][j][i];
      if (i<3) a_s[(size_t)n*3+i]=v; else a_d[(size_t)n*3+(i-3)]=v;
    }
  }
}

// ---- CSR build: histogram of dst ----
__global__ __launch_bounds__(256)
void deg_kernel(const int* __restrict__ ei, int* __restrict__ deg, int nE)
{
  int e = blockIdx.x*256 + threadIdx.x;
  if (e < nE) atomicAdd(&deg[ei[nE + e]], 1);
}

// ---- CSR build: single-block exclusive scan (nN ~ 50K) ----
__global__ __launch_bounds__(SCAN_T)
void scan_kernel(const int* __restrict__ deg, int* __restrict__ rowptr,
                 int* __restrict__ cursor, int nN)
{
  __shared__ int sums[SCAN_T];
  int t = threadIdx.x;
  int K = (nN + SCAN_T - 1) / SCAN_T;
  int start = t * K;
  int tot = 0;
  for (int i=0;i<K;i++){ int idx = start+i; if (idx < nN) tot += deg[idx]; }
  sums[t] = tot;
  __syncthreads();
  for (int off=1; off<SCAN_T; off<<=1){
    int v = sums[t];
    int add = (t >= off) ? sums[t-off] : 0;
    __syncthreads();
    sums[t] = v + add;
    __syncthreads();
  }
  int run = (t==0) ? 0 : sums[t-1];
  for (int i=0;i<K;i++){
    int idx = start+i;
    if (idx < nN){ rowptr[idx]=run; cursor[idx]=run; run += deg[idx]; }
  }
  if (t == SCAN_T-1) rowptr[nN] = run;
}

// ---- CSR build: scatter src ids into rows ----
__global__ __launch_bounds__(256)
void scatter_kernel(const int* __restrict__ ei, int* __restrict__ cursor,
                    int* __restrict__ csr, int nE)
{
  int e = blockIdx.x*256 + threadIdx.x;
  if (e < nE){
    int s = ei[e], d = ei[nE + e];
    int pos = atomicAdd(&cursor[d], 1);
    csr[pos] = s;
  }
}

// ---- fused per-node: softmax over row + message gather + epilogue GEMM ----
__global__ __launch_bounds__(256)
void gather_kernel(const int* __restrict__ rowptr, const int* __restrict__ csr,
                   const float* __restrict__ a_s, const float* __restrict__ a_d,
                   const float* __restrict__ xh, const float* __restrict__ h,
                   const float* __restrict__ gat_bias, const float* __restrict__ out_w,
                   const float* __restrict__ out_b, float* __restrict__ out, int nN)
{
  int wave = threadIdx.x >> 6, lane = threadIdx.x & 63;
  int n = blockIdx.x*4 + wave;
  if (n >= nN) return;

  int ro  = rowptr[n];
  int deg = rowptr[n+1] - ro;
  int degT = deg + 1;                       // + implicit self loop
  float ad0 = a_d[(size_t)n*3+0], ad1 = a_d[(size_t)n*3+1], ad2 = a_d[(size_t)n*3+2];

  // pass 1: row max per head
  float m0=-1e30f, m1=-1e30f, m2=-1e30f;
  for (int base=0; base<degT; base+=64){
    int i = base + lane;
    if (i < degT){
      int s = (i < deg) ? csr[ro+i] : n;
      float e0 = a_s[(size_t)s*3+0] + ad0; e0 = e0>0.f ? e0 : NEG*e0;
      float e1 = a_s[(size_t)s*3+1] + ad1; e1 = e1>0.f ? e1 : NEG*e1;
      float e2 = a_s[(size_t)s*3+2] + ad2; e2 = e2>0.f ? e2 : NEG*e2;
      m0 = fmaxf(m0,e0); m1 = fmaxf(m1,e1); m2 = fmaxf(m2,e2);
    }
  }
  #pragma unroll
  for (int off=1; off<64; off<<=1){
    m0 = fmaxf(m0, __shfl_xor(m0, off));
    m1 = fmaxf(m1, __shfl_xor(m1, off));
    m2 = fmaxf(m2, __shfl_xor(m2, off));
  }

  // pass 2: row denom per head
  float d0=0.f, d1=0.f, d2=0.f;
  for (int base=0; base<degT; base+=64){
    int i = base + lane;
    if (i < degT){
      int s = (i < deg) ? csr[ro+i] : n;
      float e0 = a_s[(size_t)s*3+0] + ad0; e0 = e0>0.f ? e0 : NEG*e0;
      float e1 = a_s[(size_t)s*3+1] + ad1; e1 = e1>0.f ? e1 : NEG*e1;
      float e2 = a_s[(size_t)s*3+2] + ad2; e2 = e2>0.f ? e2 : NEG*e2;
      d0 += __expf(e0-m0); d1 += __expf(e1-m1); d2 += __expf(e2-m2);
    }
  }
  #pragma unroll
  for (int off=1; off<64; off<<=1){
    d0 += __shfl_xor(d0, off);
    d1 += __shfl_xor(d1, off);
    d2 += __shfl_xor(d2, off);
  }
  // fold head-mean (/3) into the softmax weight
  float w0 = 1.f/(3.f*(d0+1e-16f));
  float w1 = 1.f/(3.f*(d1+1e-16f));
  float w2 = 1.f/(3.f*(d2+1e-16f));

  // pass 3: weighted message accumulation, 2 channels per lane
  int c0 = lane, c1 = lane + 64;
  float acc0 = 0.f, acc1 = 0.f;
  for (int base=0; base<degT; base+=64){
    int i = base + lane;
    int sReg = n; float p0=0.f, p1=0.f, p2=0.f;
    if (i < degT){
      int s = (i < deg) ? csr[ro+i] : n;
      sReg = s;
      float e0 = a_s[(size_t)s*3+0] + ad0; e0 = e0>0.f ? e0 : NEG*e0;
      float e1 = a_s[(size_t)s*3+1] + ad1; e1 = e1>0.f ? e1 : NEG*e1;
      float e2 = a_s[(size_t)s*3+2] + ad2; e2 = e2>0.f ? e2 : NEG*e2;
      p0 = __expf(e0-m0)*w0; p1 = __expf(e1-m1)*w1; p2 = __expf(e2-m2)*w2;
    }
    int cnt = min(64, degT - base);
    for (int j=0;j<cnt;j++){
      int   s  = __shfl(sReg, j);
      float A0 = __shfl(p0, j);
      float A1 = __shfl(p1, j);
      float A2 = __shfl(p2, j);
      const float* xs = xh + (size_t)s*384;
      acc0 += A0*xs[c0] + A1*xs[128+c0] + A2*xs[256+c0];
      acc1 += A0*xs[c1] + A1*xs[128+c1] + A2*xs[256+c1];
    }
  }

  // epilogue: + bias + residual, then (128 -> 4) GEMM
  float v0 = acc0 + gat_bias[c0] + h[(size_t)n*128+c0];
  float v1 = acc1 + gat_bias[c1] + h[(size_t)n*128+c1];
  float p[4];
  #pragma unroll
  for (int j=0;j<4;j++) p[j] = v0*out_w[c0*4+j] + v1*out_w[c1*4+j];
  #pragma unroll
  for (int off=32; off; off>>=1){
    #pragma unroll
    for (int j=0;j<4;j++) p[j] += __shfl_down(p[j], off);
  }
  if (lane==0){
    #pragma unroll
    for (int j=0;j<4;j++) out[(size_t)n*4+j] = p[j] + out_b[j];
  }
}

extern "C" void kernel_launch(void* const* d_in, const int* in_sizes, int n_in,
                              void* d_out, int out_size, void* d_ws, size_t ws_size,
                              hipStream_t stream) {
  const float* x       = (const float*)d_in[0];
  const float* emb_w   = (const float*)d_in[1];
  const float* emb_b   = (const float*)d_in[2];
  const float* gat_w   = (const float*)d_in[3];
  const float* att_src = (const float*)d_in[4];
  const float* att_dst = (const float*)d_in[5];
  const float* gat_bias= (const float*)d_in[6];
  const float* out_w   = (const float*)d_in[7];
  const float* out_b   = (const float*)d_in[8];
  const int*   ei      = (const int*)d_in[9];
  float* out = (float*)d_out;

  int nN = in_sizes[0]/9;
  int nE = in_sizes[9]/2;

  char* p = (char*)d_ws;
  auto alloc = [&](size_t bytes)->char*{
    char* r = p; p += (bytes + 255) & ~(size_t)255; return r;
  };
  float* h_buf  = (float*)alloc((size_t)nN*128*4);
  float* xh     = (float*)alloc((size_t)nN*384*4);
  float* a_s    = (float*)alloc((size_t)nN*3*4);
  float* a_d    = (float*)alloc((size_t)nN*3*4);
  int*   deg    = (int*)  alloc((size_t)nN*4);
  int*   rowptr = (int*)  alloc(((size_t)nN+1)*4);
  int*   cursor = (int*)  alloc((size_t)nN*4);
  int*   csr    = (int*)  alloc((size_t)nE*4);

  hipMemsetAsync(deg, 0, (size_t)nN*4, stream);

  node_embed_kernel<<<(nN+NB-1)/NB, 128, 0, stream>>>(
      x, emb_w, emb_b, gat_w, att_src, att_dst, h_buf, xh, a_s, a_d, nN);

  deg_kernel<<<(nE+255)/256, 256, 0, stream>>>(ei, deg, nE);
  scan_kernel<<<1, SCAN_T, 0, stream>>>(deg, rowptr, cursor, nN);
  scatter_kernel<<<(nE+255)/256, 256, 0, stream>>>(ei, cursor, csr, nE);

  gather_kernel<<<(nN+3)/4, 256, 0, stream>>>(
      rowptr, csr, a_s, a_d, xh, h_buf, gat_bias, out_w, out_b, out, nN);
}

// Round 3
// 418.293 us; speedup vs baseline: 1.2421x; 1.0740x over previous
//
#include <hip/hip_runtime.h>
#include <hip/hip_bf16.h>
#include <cstdint>

#define NB 8
#define NEG 0.2f
#define SCAN_T 1024

typedef __attribute__((ext_vector_type(8))) short bf16x8;
typedef __attribute__((ext_vector_type(4))) float f32x4;

__device__ __forceinline__ float bf2f(unsigned short u){
  return __uint_as_float(((unsigned)u)<<16);
}
__device__ __forceinline__ unsigned short f2bf(float f){
  __hip_bfloat16 b = __float2bfloat16(f);   // RNE
  return *reinterpret_cast<unsigned short*>(&b);
}

// ---- prep: w_att[6][128] = gat_w_h @ att ; Bt[128c][384k] = gat_w^T / 3 (bf16) ----
__global__ __launch_bounds__(384)
void prep_kernel(const float* __restrict__ gat_w, const float* __restrict__ att_src,
                 const float* __restrict__ att_dst, float* __restrict__ w_att_s,
                 float* __restrict__ w_att_d, unsigned short* __restrict__ Bt)
{
  int t = threadIdx.x;          // t = h*128 + k
  int h = t >> 7, k = t & 127;
  float ws = 0.f, wd = 0.f;
  for (int c = 0; c < 128; c++){
    float g = gat_w[k*384 + h*128 + c];
    ws += g * att_src[h*128 + c];
    wd += g * att_dst[h*128 + c];
  }
  w_att_s[t] = ws;              // layout [h][k]
  w_att_d[t] = wd;
  for (int c = 0; c < 128; c++){
    Bt[(size_t)c*384 + t] = f2bf(gat_w[k*384 + h*128 + c] * (1.f/3.f));
  }
}

// ---- embed: h = x@emb_w + emb_b (f32 + bf16) ; a_s/a_d = h @ w_att ----
__global__ __launch_bounds__(128)
void embed_kernel(const float* __restrict__ x, const float* __restrict__ emb_w,
                  const float* __restrict__ emb_b, const float* __restrict__ w_att_s,
                  const float* __restrict__ w_att_d, float* __restrict__ h_out,
                  unsigned short* __restrict__ h_bf, float* __restrict__ a_s,
                  float* __restrict__ a_d, int nN)
{
  __shared__ float xs[NB][12];
  int t = threadIdx.x;          // 0..127 = channel
  int n0 = blockIdx.x * NB;

  if (t < NB*9){
    int j = t/9, k = t - j*9;
    int n = n0 + j;
    xs[j][k] = (n < nN) ? x[(size_t)n*9 + k] : 0.f;
  }
  __syncthreads();

  float bb = emb_b[t];
  float ws0=w_att_s[t], ws1=w_att_s[128+t], ws2=w_att_s[256+t];
  float wd0=w_att_d[t], wd1=w_att_d[128+t], wd2=w_att_d[256+t];

  float hv[NB];
  #pragma unroll
  for (int j=0;j<NB;j++){
    float acc = bb;
    #pragma unroll
    for (int k=0;k<9;k++) acc += xs[j][k]*emb_w[k*128+t];
    hv[j] = acc;
    int n = n0 + j;
    if (n < nN){
      h_out[(size_t)n*128 + t] = acc;
      h_bf [(size_t)n*128 + t] = f2bf(acc);
    }
  }

  __shared__ float red[2][NB][6];
  int wv = t>>6, ln = t&63;
  #pragma unroll
  for (int j=0;j<NB;j++){
    float pr[6] = {hv[j]*ws0, hv[j]*ws1, hv[j]*ws2,
                   hv[j]*wd0, hv[j]*wd1, hv[j]*wd2};
    #pragma unroll
    for (int off=32; off; off>>=1){
      #pragma unroll
      for (int i=0;i<6;i++) pr[i] += __shfl_down(pr[i], off);
    }
    if (ln==0){
      #pragma unroll
      for (int i=0;i<6;i++) red[wv][j][i]=pr[i];
    }
  }
  __syncthreads();
  if (t < NB*6){
    int j=t/6, i=t-j*6;
    int n=n0+j;
    if (n<nN){
      float v = red[0][j][i]+red[1][j][i];
      if (i<3) a_s[(size_t)n*3+i]=v; else a_d[(size_t)n*3+(i-3)]=v;
    }
  }
}

// ---- CSR build ----
__global__ __launch_bounds__(256)
void deg_kernel(const int* __restrict__ ei, int* __restrict__ deg, int nE)
{
  int e = blockIdx.x*256 + threadIdx.x;
  if (e < nE) atomicAdd(&deg[ei[nE + e]], 1);
}

__global__ __launch_bounds__(SCAN_T)
void scan_kernel(const int* __restrict__ deg, int* __restrict__ rowptr,
                 int* __restrict__ cursor, int nN)
{
  __shared__ int sums[SCAN_T];
  int t = threadIdx.x;
  int K = (nN + SCAN_T - 1) / SCAN_T;
  int start = t * K;
  int tot = 0;
  for (int i=0;i<K;i++){ int idx = start+i; if (idx < nN) tot += deg[idx]; }
  sums[t] = tot;
  __syncthreads();
  for (int off=1; off<SCAN_T; off<<=1){
    int v = sums[t];
    int add = (t >= off) ? sums[t-off] : 0;
    __syncthreads();
    sums[t] = v + add;
    __syncthreads();
  }
  int run = (t==0) ? 0 : sums[t-1];
  for (int i=0;i<K;i++){
    int idx = start+i;
    if (idx < nN){ rowptr[idx]=run; cursor[idx]=run; run += deg[idx]; }
  }
  if (t == SCAN_T-1) rowptr[nN] = run;
}

__global__ __launch_bounds__(256)
void scatter_kernel(const int* __restrict__ ei, int* __restrict__ cursor,
                    int* __restrict__ csr, int nE)
{
  int e = blockIdx.x*256 + threadIdx.x;
  if (e < nE){
    int s = ei[e], d = ei[nE + e];
    int pos = atomicAdd(&cursor[d], 1);
    csr[pos] = s;
  }
}

// ---- gather: per-node softmax + weighted aggregation of h_bf -> hagg bf16 ----
__global__ __launch_bounds__(256)
void gather_kernel(const int* __restrict__ rowptr, const int* __restrict__ csr,
                   const float* __restrict__ a_s, const float* __restrict__ a_d,
                   const unsigned short* __restrict__ h_bf,
                   unsigned short* __restrict__ hagg, int nN)
{
  int wave = threadIdx.x >> 6, lane = threadIdx.x & 63;
  int n = blockIdx.x*4 + wave;
  if (n >= nN) return;

  int ro  = rowptr[n];
  int deg = rowptr[n+1] - ro;
  int degT = deg + 1;                       // + self loop
  float ad0 = a_d[(size_t)n*3+0], ad1 = a_d[(size_t)n*3+1], ad2 = a_d[(size_t)n*3+2];

  // pass 1: row max
  float m0=-1e30f, m1=-1e30f, m2=-1e30f;
  for (int base=0; base<degT; base+=64){
    int i = base + lane;
    if (i < degT){
      int s = (i < deg) ? csr[ro+i] : n;
      float e0 = a_s[(size_t)s*3+0] + ad0; e0 = e0>0.f ? e0 : NEG*e0;
      float e1 = a_s[(size_t)s*3+1] + ad1; e1 = e1>0.f ? e1 : NEG*e1;
      float e2 = a_s[(size_t)s*3+2] + ad2; e2 = e2>0.f ? e2 : NEG*e2;
      m0 = fmaxf(m0,e0); m1 = fmaxf(m1,e1); m2 = fmaxf(m2,e2);
    }
  }
  #pragma unroll
  for (int off=1; off<64; off<<=1){
    m0 = fmaxf(m0, __shfl_xor(m0, off));
    m1 = fmaxf(m1, __shfl_xor(m1, off));
    m2 = fmaxf(m2, __shfl_xor(m2, off));
  }

  // pass 2: row denom
  float d0=0.f, d1=0.f, d2=0.f;
  for (int base=0; base<degT; base+=64){
    int i = base + lane;
    if (i < degT){
      int s = (i < deg) ? csr[ro+i] : n;
      float e0 = a_s[(size_t)s*3+0] + ad0; e0 = e0>0.f ? e0 : NEG*e0;
      float e1 = a_s[(size_t)s*3+1] + ad1; e1 = e1>0.f ? e1 : NEG*e1;
      float e2 = a_s[(size_t)s*3+2] + ad2; e2 = e2>0.f ? e2 : NEG*e2;
      d0 += __expf(e0-m0); d1 += __expf(e1-m1); d2 += __expf(e2-m2);
    }
  }
  #pragma unroll
  for (int off=1; off<64; off<<=1){
    d0 += __shfl_xor(d0, off);
    d1 += __shfl_xor(d1, off);
    d2 += __shfl_xor(d2, off);
  }
  float w0 = 1.f/(d0+1e-16f);
  float w1 = 1.f/(d1+1e-16f);
  float w2 = 1.f/(d2+1e-16f);

  // pass 3: weighted aggregation of h (2 channels/lane)
  float acc00=0.f, acc01=0.f, acc10=0.f, acc11=0.f, acc20=0.f, acc21=0.f;
  for (int base=0; base<degT; base+=64){
    int i = base + lane;
    int sReg = n; float p0=0.f, p1=0.f, p2=0.f;
    if (i < degT){
      int s = (i < deg) ? csr[ro+i] : n;
      sReg = s;
      float e0 = a_s[(size_t)s*3+0] + ad0; e0 = e0>0.f ? e0 : NEG*e0;
      float e1 = a_s[(size_t)s*3+1] + ad1; e1 = e1>0.f ? e1 : NEG*e1;
      float e2 = a_s[(size_t)s*3+2] + ad2; e2 = e2>0.f ? e2 : NEG*e2;
      p0 = __expf(e0-m0)*w0; p1 = __expf(e1-m1)*w1; p2 = __expf(e2-m2)*w2;
    }
    int cnt = min(64, degT - base);
    for (int j=0;j<cnt;j++){
      int   s  = __shfl(sReg, j);
      float A0 = __shfl(p0, j);
      float A1 = __shfl(p1, j);
      float A2 = __shfl(p2, j);
      ushort2 hv = *(const ushort2*)(h_bf + (size_t)s*128 + 2*lane);
      float f0 = bf2f(hv.x), f1 = bf2f(hv.y);
      acc00 += A0*f0; acc01 += A0*f1;
      acc10 += A1*f0; acc11 += A1*f1;
      acc20 += A2*f0; acc21 += A2*f1;
    }
  }

  size_t base = (size_t)n*384 + 2*lane;
  ushort2 o0 = {f2bf(acc00), f2bf(acc01)};
  ushort2 o1 = {f2bf(acc10), f2bf(acc11)};
  ushort2 o2 = {f2bf(acc20), f2bf(acc21)};
  *(ushort2*)(hagg + base      ) = o0;
  *(ushort2*)(hagg + base + 128) = o1;
  *(ushort2*)(hagg + base + 256) = o2;
}

// ---- gemm2: out = ((hagg @ Bt^T) + bias + h) @ out_w + out_b via MFMA ----
__global__ __launch_bounds__(256)
void gemm2_kernel(const unsigned short* __restrict__ hagg,
                  const unsigned short* __restrict__ Bt,
                  const float* __restrict__ h, const float* __restrict__ gat_bias,
                  const float* __restrict__ out_w, const float* __restrict__ out_b,
                  float* __restrict__ out, int nN)
{
  int wave = threadIdx.x >> 6, lane = threadIdx.x & 63;
  int r0 = blockIdx.x*64 + wave*16;
  int cl = lane & 15;        // A-row / B-col within fragment
  int kg = lane >> 4;        // k-group
  int rowA = r0 + cl;
  int rowAc = min(rowA, nN-1);

  f32x4 acc[8];
  #pragma unroll
  for (int f=0;f<8;f++) acc[f] = (f32x4){0.f,0.f,0.f,0.f};

  #pragma unroll
  for (int ks=0; ks<12; ks++){
    int k = ks*32 + kg*8;
    bf16x8 a = *(const bf16x8*)(hagg + (size_t)rowAc*384 + k);
    #pragma unroll
    for (int f=0;f<8;f++){
      bf16x8 b = *(const bf16x8*)(Bt + (size_t)(f*16 + cl)*384 + k);
      acc[f] = __builtin_amdgcn_mfma_f32_16x16x32_bf16(a, b, acc[f], 0, 0, 0);
    }
  }

  // epilogue: x_new = acc + gat_bias + h ; p = x_new @ out_w ; reduce over cols
  float p[4][4];
  #pragma unroll
  for (int r=0;r<4;r++)
    #pragma unroll
    for (int j=0;j<4;j++) p[r][j]=0.f;

  #pragma unroll
  for (int f=0;f<8;f++){
    int col = f*16 + cl;
    float bias = gat_bias[col];
    float w0=out_w[col*4+0], w1=out_w[col*4+1], w2=out_w[col*4+2], w3=out_w[col*4+3];
    #pragma unroll
    for (int r=0;r<4;r++){
      int row = r0 + kg*4 + r;
      float xn = acc[f][r] + bias + ((row < nN) ? h[(size_t)row*128 + col] : 0.f);
      p[r][0] += xn*w0; p[r][1] += xn*w1; p[r][2] += xn*w2; p[r][3] += xn*w3;
    }
  }
  #pragma unroll
  for (int off=1; off<16; off<<=1){
    #pragma unroll
    for (int r=0;r<4;r++)
      #pragma unroll
      for (int j=0;j<4;j++) p[r][j] += __shfl_xor(p[r][j], off);
  }
  if (cl == 0){
    #pragma unroll
    for (int r=0;r<4;r++){
      int row = r0 + kg*4 + r;
      if (row < nN){
        #pragma unroll
        for (int j=0;j<4;j++) out[(size_t)row*4+j] = p[r][j] + out_b[j];
      }
    }
  }
}

extern "C" void kernel_launch(void* const* d_in, const int* in_sizes, int n_in,
                              void* d_out, int out_size, void* d_ws, size_t ws_size,
                              hipStream_t stream) {
  const float* x       = (const float*)d_in[0];
  const float* emb_w   = (const float*)d_in[1];
  const float* emb_b   = (const float*)d_in[2];
  const float* gat_w   = (const float*)d_in[3];
  const float* att_src = (const float*)d_in[4];
  const float* att_dst = (const float*)d_in[5];
  const float* gat_bias= (const float*)d_in[6];
  const float* out_w   = (const float*)d_in[7];
  const float* out_b   = (const float*)d_in[8];
  const int*   ei      = (const int*)d_in[9];
  float* out = (float*)d_out;

  int nN = in_sizes[0]/9;
  int nE = in_sizes[9]/2;

  char* p = (char*)d_ws;
  auto alloc = [&](size_t bytes)->char*{
    char* r = p; p += (bytes + 255) & ~(size_t)255; return r;
  };
  float*          h_buf  = (float*)         alloc((size_t)nN*128*4);
  unsigned short* h_bf   = (unsigned short*)alloc((size_t)nN*128*2);
  float*          a_s    = (float*)         alloc((size_t)nN*3*4);
  float*          a_d    = (float*)         alloc((size_t)nN*3*4);
  float*          w_att_s= (float*)         alloc(384*4);
  float*          w_att_d= (float*)         alloc(384*4);
  unsigned short* Bt     = (unsigned short*)alloc((size_t)128*384*2);
  int*            deg    = (int*)           alloc((size_t)nN*4);
  int*            rowptr = (int*)           alloc(((size_t)nN+1)*4);
  int*            cursor = (int*)           alloc((size_t)nN*4);
  int*            csr    = (int*)           alloc((size_t)nE*4);
  unsigned short* hagg   = (unsigned short*)alloc((size_t)nN*384*2);

  hipMemsetAsync(deg, 0, (size_t)nN*4, stream);

  prep_kernel<<<1, 384, 0, stream>>>(gat_w, att_src, att_dst, w_att_s, w_att_d, Bt);

  embed_kernel<<<(nN+NB-1)/NB, 128, 0, stream>>>(
      x, emb_w, emb_b, w_att_s, w_att_d, h_buf, h_bf, a_s, a_d, nN);

  deg_kernel<<<(nE+255)/256, 256, 0, stream>>>(ei, deg, nE);
  scan_kernel<<<1, SCAN_T, 0, stream>>>(deg, rowptr, cursor, nN);
  scatter_kernel<<<(nE+255)/256, 256, 0, stream>>>(ei, cursor, csr, nE);

  gather_kernel<<<(nN+3)/4, 256, 0, stream>>>(
      rowptr, csr, a_s, a_d, h_bf, hagg, nN);

  gemm2_kernel<<<(nN+63)/64, 256, 0, stream>>>(
      hagg, Bt, h_buf, gat_bias, out_w, out_b, out, nN);
}

// Round 4
// 276.544 us; speedup vs baseline: 1.8787x; 1.5126x over previous
//
#include <hip/hip_runtime.h>
#include <hip/hip_bf16.h>
#include <cstdint>

#define NB 8
#define NEG 0.2f
#define SBS 256        // scan block size
#define SCAN2_T 1024   // block-sum scan width

typedef __attribute__((ext_vector_type(8))) short bf16x8;
typedef __attribute__((ext_vector_type(4))) float f32x4;

__device__ __forceinline__ float bf2f(unsigned short u){
  return __uint_as_float(((unsigned)u)<<16);
}
__device__ __forceinline__ unsigned short f2bf(float f){
  __hip_bfloat16 b = __float2bfloat16(f);   // RNE
  return *reinterpret_cast<unsigned short*>(&b);
}

// ---- prep A: w_att[6][128] = gat_w_h @ att, one wave per output ----
__global__ __launch_bounds__(256)
void watt_kernel(const float* __restrict__ gat_w, const float* __restrict__ att_src,
                 const float* __restrict__ att_dst, float* __restrict__ w_att_s,
                 float* __restrict__ w_att_d)
{
  int wave = threadIdx.x >> 6, lane = threadIdx.x & 63;
  int o = blockIdx.x*4 + wave;          // 0..767
  if (o >= 768) return;
  int sd = o >> 1;                      // interleave s/d for balance? simpler: o<384 -> s
  (void)sd;
  int isD = (o >= 384);
  int t = isD ? (o - 384) : o;          // h*128 + k
  int h = t >> 7, k = t & 127;
  const float* att = isD ? att_dst : att_src;
  int c = 2*lane;
  float g0 = gat_w[(size_t)k*384 + h*128 + c];
  float g1 = gat_w[(size_t)k*384 + h*128 + c + 1];
  float dot = g0*att[h*128+c] + g1*att[h*128+c+1];
  #pragma unroll
  for (int off=32; off; off>>=1) dot += __shfl_down(dot, off);
  if (lane==0){
    if (isD) w_att_d[t] = dot; else w_att_s[t] = dot;
  }
}

// ---- prep B: Bt[c][384] = gat_w^T / 3 in bf16 ----
__global__ __launch_bounds__(256)
void bt_kernel(const float* __restrict__ gat_w, unsigned short* __restrict__ Bt)
{
  int i = blockIdx.x*256 + threadIdx.x;       // 0..49151
  if (i >= 128*384) return;
  int c = i / 384, t = i - c*384;
  int h = t >> 7, k = t & 127;
  Bt[i] = f2bf(gat_w[(size_t)k*384 + h*128 + c] * (1.f/3.f));
}

// ---- embed: h = x@emb_w + emb_b (f32 + bf16) ; a_s/a_d = h @ w_att ----
__global__ __launch_bounds__(128)
void embed_kernel(const float* __restrict__ x, const float* __restrict__ emb_w,
                  const float* __restrict__ emb_b, const float* __restrict__ w_att_s,
                  const float* __restrict__ w_att_d, float* __restrict__ h_out,
                  unsigned short* __restrict__ h_bf, float* __restrict__ a_s,
                  float* __restrict__ a_d, int nN)
{
  __shared__ float xs[NB][12];
  int t = threadIdx.x;          // 0..127 = channel
  int n0 = blockIdx.x * NB;

  if (t < NB*9){
    int j = t/9, k = t - j*9;
    int n = n0 + j;
    xs[j][k] = (n < nN) ? x[(size_t)n*9 + k] : 0.f;
  }
  __syncthreads();

  float bb = emb_b[t];
  float ws0=w_att_s[t], ws1=w_att_s[128+t], ws2=w_att_s[256+t];
  float wd0=w_att_d[t], wd1=w_att_d[128+t], wd2=w_att_d[256+t];

  float hv[NB];
  #pragma unroll
  for (int j=0;j<NB;j++){
    float acc = bb;
    #pragma unroll
    for (int k=0;k<9;k++) acc += xs[j][k]*emb_w[k*128+t];
    hv[j] = acc;
    int n = n0 + j;
    if (n < nN){
      h_out[(size_t)n*128 + t] = acc;
      h_bf [(size_t)n*128 + t] = f2bf(acc);
    }
  }

  __shared__ float red[2][NB][6];
  int wv = t>>6, ln = t&63;
  #pragma unroll
  for (int j=0;j<NB;j++){
    float pr[6] = {hv[j]*ws0, hv[j]*ws1, hv[j]*ws2,
                   hv[j]*wd0, hv[j]*wd1, hv[j]*wd2};
    #pragma unroll
    for (int off=32; off; off>>=1){
      #pragma unroll
      for (int i=0;i<6;i++) pr[i] += __shfl_down(pr[i], off);
    }
    if (ln==0){
      #pragma unroll
      for (int i=0;i<6;i++) red[wv][j][i]=pr[i];
    }
  }
  __syncthreads();
  if (t < NB*6){
    int j=t/6, i=t-j*6;
    int n=n0+j;
    if (n<nN){
      float v = red[0][j][i]+red[1][j][i];
      if (i<3) a_s[(size_t)n*3+i]=v; else a_d[(size_t)n*3+(i-3)]=v;
    }
  }
}

// ---- CSR build ----
__global__ __launch_bounds__(256)
void deg_kernel(const int* __restrict__ ei, int* __restrict__ deg, int nE)
{
  int e = blockIdx.x*256 + threadIdx.x;
  if (e < nE) atomicAdd(&deg[ei[nE + e]], 1);
}

__global__ __launch_bounds__(SBS)
void blocksum_kernel(const int* __restrict__ deg, int* __restrict__ bsum, int nN)
{
  int i = blockIdx.x*SBS + threadIdx.x;
  int v = (i < nN) ? deg[i] : 0;
  #pragma unroll
  for (int off=32; off; off>>=1) v += __shfl_down(v, off);
  __shared__ int ws[SBS/64];
  if ((threadIdx.x&63)==0) ws[threadIdx.x>>6] = v;
  __syncthreads();
  if (threadIdx.x==0){
    int s=0;
    #pragma unroll
    for (int i2=0;i2<SBS/64;i2++) s += ws[i2];
    bsum[blockIdx.x]=s;
  }
}

__global__ __launch_bounds__(SCAN2_T)
void scansum_kernel(const int* __restrict__ bsum, int* __restrict__ boff, int nB)
{
  __shared__ int s[SCAN2_T];
  int t = threadIdx.x;
  int v = (t < nB) ? bsum[t] : 0;
  s[t] = v;
  __syncthreads();
  for (int off=1; off<SCAN2_T; off<<=1){
    int add = (t >= off) ? s[t-off] : 0;
    __syncthreads();
    s[t] += add;
    __syncthreads();
  }
  if (t < nB) boff[t] = (t==0) ? 0 : s[t-1];
}

__global__ __launch_bounds__(SBS)
void blockscan_kernel(const int* __restrict__ deg, const int* __restrict__ boff,
                      int* __restrict__ rowptr, int* __restrict__ cursor, int nN)
{
  __shared__ int s[SBS];
  int t = threadIdx.x;
  int i = blockIdx.x*SBS + t;
  int v = (i < nN) ? deg[i] : 0;
  s[t] = v;
  __syncthreads();
  for (int off=1; off<SBS; off<<=1){
    int add = (t >= off) ? s[t-off] : 0;
    __syncthreads();
    s[t] += add;
    __syncthreads();
  }
  int excl = boff[blockIdx.x] + ((t==0) ? 0 : s[t-1]);
  if (i < nN){ rowptr[i] = excl; cursor[i] = excl; }
  if (i == nN-1) rowptr[nN] = excl + v;
}

__global__ __launch_bounds__(256)
void scatter_kernel(const int* __restrict__ ei, int* __restrict__ cursor,
                    int* __restrict__ csr, int nE)
{
  int e = blockIdx.x*256 + threadIdx.x;
  if (e < nE){
    int s = ei[e], d = ei[nE + e];
    int pos = atomicAdd(&cursor[d], 1);
    csr[pos] = s;
  }
}

// ---- gather: SINGLE pass — unnormalized Σexp(e)·h and Σexp(e), divide once ----
__global__ __launch_bounds__(256)
void gather_kernel(const int* __restrict__ rowptr, const int* __restrict__ csr,
                   const float* __restrict__ a_s, const float* __restrict__ a_d,
                   const unsigned short* __restrict__ h_bf,
                   unsigned short* __restrict__ hagg, int nN)
{
  int wave = threadIdx.x >> 6, lane = threadIdx.x & 63;
  int n = blockIdx.x*4 + wave;
  if (n >= nN) return;

  int ro  = rowptr[n];
  int deg = rowptr[n+1] - ro;
  int degT = deg + 1;                       // + self loop
  float ad0 = a_d[(size_t)n*3+0], ad1 = a_d[(size_t)n*3+1], ad2 = a_d[(size_t)n*3+2];

  float d0=0.f, d1=0.f, d2=0.f;
  float acc00=0.f, acc01=0.f, acc10=0.f, acc11=0.f, acc20=0.f, acc21=0.f;

  for (int base=0; base<degT; base+=64){
    int i = base + lane;
    int sReg = n; float p0=0.f, p1=0.f, p2=0.f;
    if (i < degT){
      int s = (i < deg) ? csr[ro+i] : n;
      sReg = s;
      float e0 = a_s[(size_t)s*3+0] + ad0; e0 = e0>0.f ? e0 : NEG*e0;
      float e1 = a_s[(size_t)s*3+1] + ad1; e1 = e1>0.f ? e1 : NEG*e1;
      float e2 = a_s[(size_t)s*3+2] + ad2; e2 = e2>0.f ? e2 : NEG*e2;
      p0 = __expf(e0); p1 = __expf(e1); p2 = __expf(e2);
      d0 += p0; d1 += p1; d2 += p2;
    }
    int cnt = min(64, degT - base);
    for (int j=0;j<cnt;j++){
      int   s  = __shfl(sReg, j);
      float A0 = __shfl(p0, j);
      float A1 = __shfl(p1, j);
      float A2 = __shfl(p2, j);
      ushort2 hv = *(const ushort2*)(h_bf + (size_t)s*128 + 2*lane);
      float f0 = bf2f(hv.x), f1 = bf2f(hv.y);
      acc00 += A0*f0; acc01 += A0*f1;
      acc10 += A1*f0; acc11 += A1*f1;
      acc20 += A2*f0; acc21 += A2*f1;
    }
  }
  #pragma unroll
  for (int off=1; off<64; off<<=1){
    d0 += __shfl_xor(d0, off);
    d1 += __shfl_xor(d1, off);
    d2 += __shfl_xor(d2, off);
  }
  float w0 = 1.f/(d0+1e-16f);
  float w1 = 1.f/(d1+1e-16f);
  float w2 = 1.f/(d2+1e-16f);

  size_t base = (size_t)n*384 + 2*lane;
  ushort2 o0 = {f2bf(acc00*w0), f2bf(acc01*w0)};
  ushort2 o1 = {f2bf(acc10*w1), f2bf(acc11*w1)};
  ushort2 o2 = {f2bf(acc20*w2), f2bf(acc21*w2)};
  *(ushort2*)(hagg + base      ) = o0;
  *(ushort2*)(hagg + base + 128) = o1;
  *(ushort2*)(hagg + base + 256) = o2;
}

// ---- gemm2: out = ((hagg @ Bt^T) + bias + h) @ out_w + out_b via MFMA ----
__global__ __launch_bounds__(256)
void gemm2_kernel(const unsigned short* __restrict__ hagg,
                  const unsigned short* __restrict__ Bt,
                  const float* __restrict__ h, const float* __restrict__ gat_bias,
                  const float* __restrict__ out_w, const float* __restrict__ out_b,
                  float* __restrict__ out, int nN)
{
  int wave = threadIdx.x >> 6, lane = threadIdx.x & 63;
  int r0 = blockIdx.x*64 + wave*16;
  int cl = lane & 15;        // A-row / B-col within fragment
  int kg = lane >> 4;        // k-group
  int rowA = r0 + cl;
  int rowAc = min(rowA, nN-1);

  f32x4 acc[8];
  #pragma unroll
  for (int f=0;f<8;f++) acc[f] = (f32x4){0.f,0.f,0.f,0.f};

  #pragma unroll
  for (int ks=0; ks<12; ks++){
    int k = ks*32 + kg*8;
    bf16x8 a = *(const bf16x8*)(hagg + (size_t)rowAc*384 + k);
    #pragma unroll
    for (int f=0;f<8;f++){
      bf16x8 b = *(const bf16x8*)(Bt + (size_t)(f*16 + cl)*384 + k);
      acc[f] = __builtin_amdgcn_mfma_f32_16x16x32_bf16(a, b, acc[f], 0, 0, 0);
    }
  }

  float p[4][4];
  #pragma unroll
  for (int r=0;r<4;r++)
    #pragma unroll
    for (int j=0;j<4;j++) p[r][j]=0.f;

  #pragma unroll
  for (int f=0;f<8;f++){
    int col = f*16 + cl;
    float bias = gat_bias[col];
    float w0=out_w[col*4+0], w1=out_w[col*4+1], w2=out_w[col*4+2], w3=out_w[col*4+3];
    #pragma unroll
    for (int r=0;r<4;r++){
      int row = r0 + kg*4 + r;
      float xn = acc[f][r] + bias + ((row < nN) ? h[(size_t)row*128 + col] : 0.f);
      p[r][0] += xn*w0; p[r][1] += xn*w1; p[r][2] += xn*w2; p[r][3] += xn*w3;
    }
  }
  #pragma unroll
  for (int off=1; off<16; off<<=1){
    #pragma unroll
    for (int r=0;r<4;r++)
      #pragma unroll
      for (int j=0;j<4;j++) p[r][j] += __shfl_xor(p[r][j], off);
  }
  if (cl == 0){
    #pragma unroll
    for (int r=0;r<4;r++){
      int row = r0 + kg*4 + r;
      if (row < nN){
        #pragma unroll
        for (int j=0;j<4;j++) out[(size_t)row*4+j] = p[r][j] + out_b[j];
      }
    }
  }
}

extern "C" void kernel_launch(void* const* d_in, const int* in_sizes, int n_in,
                              void* d_out, int out_size, void* d_ws, size_t ws_size,
                              hipStream_t stream) {
  const float* x       = (const float*)d_in[0];
  const float* emb_w   = (const float*)d_in[1];
  const float* emb_b   = (const float*)d_in[2];
  const float* gat_w   = (const float*)d_in[3];
  const float* att_src = (const float*)d_in[4];
  const float* att_dst = (const float*)d_in[5];
  const float* gat_bias= (const float*)d_in[6];
  const float* out_w   = (const float*)d_in[7];
  const float* out_b   = (const float*)d_in[8];
  const int*   ei      = (const int*)d_in[9];
  float* out = (float*)d_out;

  int nN = in_sizes[0]/9;
  int nE = in_sizes[9]/2;
  int nB = (nN + SBS - 1) / SBS;

  char* p = (char*)d_ws;
  auto alloc = [&](size_t bytes)->char*{
    char* r = p; p += (bytes + 255) & ~(size_t)255; return r;
  };
  float*          h_buf  = (float*)         alloc((size_t)nN*128*4);
  unsigned short* h_bf   = (unsigned short*)alloc((size_t)nN*128*2);
  float*          a_s    = (float*)         alloc((size_t)nN*3*4);
  float*          a_d    = (float*)         alloc((size_t)nN*3*4);
  float*          w_att_s= (float*)         alloc(384*4);
  float*          w_att_d= (float*)         alloc(384*4);
  unsigned short* Bt     = (unsigned short*)alloc((size_t)128*384*2);
  int*            deg    = (int*)           alloc((size_t)nN*4);
  int*            rowptr = (int*)           alloc(((size_t)nN+1)*4);
  int*            cursor = (int*)           alloc((size_t)nN*4);
  int*            csr    = (int*)           alloc((size_t)nE*4);
  int*            bsum   = (int*)           alloc((size_t)nB*4);
  int*            boff   = (int*)           alloc((size_t)nB*4);
  unsigned short* hagg   = (unsigned short*)alloc((size_t)nN*384*2);

  hipMemsetAsync(deg, 0, (size_t)nN*4, stream);

  watt_kernel<<<192, 256, 0, stream>>>(gat_w, att_src, att_dst, w_att_s, w_att_d);
  bt_kernel<<<(128*384+255)/256, 256, 0, stream>>>(gat_w, Bt);

  embed_kernel<<<(nN+NB-1)/NB, 128, 0, stream>>>(
      x, emb_w, emb_b, w_att_s, w_att_d, h_buf, h_bf, a_s, a_d, nN);

  deg_kernel<<<(nE+255)/256, 256, 0, stream>>>(ei, deg, nE);
  blocksum_kernel<<<nB, SBS, 0, stream>>>(deg, bsum, nN);
  scansum_kernel<<<1, SCAN2_T, 0, stream>>>(bsum, boff, nB);
  blockscan_kernel<<<nB, SBS, 0, stream>>>(deg, boff, rowptr, cursor, nN);
  scatter_kernel<<<(nE+255)/256, 256, 0, stream>>>(ei, cursor, csr, nE);

  gather_kernel<<<(nN+3)/4, 256, 0, stream>>>(
      rowptr, csr, a_s, a_d, h_bf, hagg, nN);

  gemm2_kernel<<<(nN+63)/64, 256, 0, stream>>>(
      hagg, Bt, h_buf, gat_bias, out_w, out_b, out, nN);
}

// Round 5
// 245.772 us; speedup vs baseline: 2.1140x; 1.1252x over previous
//
#include <hip/hip_runtime.h>
#include <hip/hip_bf16.h>
#include <cstdint>

#define NB 8
#define NEG 0.2f
#define SBS 256        // scan block size
#define SCAN2_T 1024   // block-sum scan width
#define PADK 56        // LDS col stride (ushorts): 112B, 16B-aligned, conflict-free

typedef __attribute__((ext_vector_type(8))) short bf16x8;
typedef __attribute__((ext_vector_type(4))) float f32x4;

__device__ __forceinline__ float bf2f(unsigned short u){
  return __uint_as_float(((unsigned)u)<<16);
}
__device__ __forceinline__ unsigned short f2bf(float f){
  __hip_bfloat16 b = __float2bfloat16(f);   // RNE
  return *reinterpret_cast<unsigned short*>(&b);
}

// ---- prep A: w_att[6][128] = gat_w_h @ att, one wave per output ----
__global__ __launch_bounds__(256)
void watt_kernel(const float* __restrict__ gat_w, const float* __restrict__ att_src,
                 const float* __restrict__ att_dst, float* __restrict__ w_att_s,
                 float* __restrict__ w_att_d)
{
  int wave = threadIdx.x >> 6, lane = threadIdx.x & 63;
  int o = blockIdx.x*4 + wave;          // 0..767
  if (o >= 768) return;
  int isD = (o >= 384);
  int t = isD ? (o - 384) : o;          // h*128 + k
  int h = t >> 7, k = t & 127;
  const float* att = isD ? att_dst : att_src;
  int c = 2*lane;
  float g0 = gat_w[(size_t)k*384 + h*128 + c];
  float g1 = gat_w[(size_t)k*384 + h*128 + c + 1];
  float dot = g0*att[h*128+c] + g1*att[h*128+c+1];
  #pragma unroll
  for (int off=32; off; off>>=1) dot += __shfl_down(dot, off);
  if (lane==0){
    if (isD) w_att_d[t] = dot; else w_att_s[t] = dot;
  }
}

// ---- prep B: Bt2[ks][col][kk] = gat_w^T / 3 (bf16), staged-slice layout ----
__global__ __launch_bounds__(256)
void bt_kernel(const float* __restrict__ gat_w, unsigned short* __restrict__ Bt2)
{
  int i = blockIdx.x*256 + threadIdx.x;       // 0..49151
  if (i >= 12*128*32) return;
  int ks  = i >> 12;
  int rem = i & 4095;
  int col = rem >> 5;
  int kk  = rem & 31;
  int t = ks*32 + kk;            // 0..383 = h*128 + k
  int h = t >> 7, k = t & 127;
  Bt2[i] = f2bf(gat_w[(size_t)k*384 + h*128 + col] * (1.f/3.f));
}

// ---- embed: h = x@emb_w + emb_b (bf16 out) ; a_s/a_d = h @ w_att ----
__global__ __launch_bounds__(128)
void embed_kernel(const float* __restrict__ x, const float* __restrict__ emb_w,
                  const float* __restrict__ emb_b, const float* __restrict__ w_att_s,
                  const float* __restrict__ w_att_d,
                  unsigned short* __restrict__ h_bf, float* __restrict__ a_s,
                  float* __restrict__ a_d, int nN)
{
  __shared__ float xs[NB][12];
  int t = threadIdx.x;          // 0..127 = channel
  int n0 = blockIdx.x * NB;

  if (t < NB*9){
    int j = t/9, k = t - j*9;
    int n = n0 + j;
    xs[j][k] = (n < nN) ? x[(size_t)n*9 + k] : 0.f;
  }
  __syncthreads();

  float bb = emb_b[t];
  float ws0=w_att_s[t], ws1=w_att_s[128+t], ws2=w_att_s[256+t];
  float wd0=w_att_d[t], wd1=w_att_d[128+t], wd2=w_att_d[256+t];

  float hv[NB];
  #pragma unroll
  for (int j=0;j<NB;j++){
    float acc = bb;
    #pragma unroll
    for (int k=0;k<9;k++) acc += xs[j][k]*emb_w[k*128+t];
    hv[j] = acc;
    int n = n0 + j;
    if (n < nN) h_bf[(size_t)n*128 + t] = f2bf(acc);
  }

  __shared__ float red[2][NB][6];
  int wv = t>>6, ln = t&63;
  #pragma unroll
  for (int j=0;j<NB;j++){
    float pr[6] = {hv[j]*ws0, hv[j]*ws1, hv[j]*ws2,
                   hv[j]*wd0, hv[j]*wd1, hv[j]*wd2};
    #pragma unroll
    for (int off=32; off; off>>=1){
      #pragma unroll
      for (int i=0;i<6;i++) pr[i] += __shfl_down(pr[i], off);
    }
    if (ln==0){
      #pragma unroll
      for (int i=0;i<6;i++) red[wv][j][i]=pr[i];
    }
  }
  __syncthreads();
  if (t < NB*6){
    int j=t/6, i=t-j*6;
    int n=n0+j;
    if (n<nN){
      float v = red[0][j][i]+red[1][j][i];
      if (i<3) a_s[(size_t)n*3+i]=v; else a_d[(size_t)n*3+(i-3)]=v;
    }
  }
}

// ---- CSR build ----
__global__ __launch_bounds__(256)
void deg_kernel(const int* __restrict__ ei, int* __restrict__ deg, int nE)
{
  int e = blockIdx.x*256 + threadIdx.x;
  if (e < nE) atomicAdd(&deg[ei[nE + e]], 1);
}

__global__ __launch_bounds__(SBS)
void blocksum_kernel(const int* __restrict__ deg, int* __restrict__ bsum, int nN)
{
  int i = blockIdx.x*SBS + threadIdx.x;
  int v = (i < nN) ? deg[i] : 0;
  #pragma unroll
  for (int off=32; off; off>>=1) v += __shfl_down(v, off);
  __shared__ int ws[SBS/64];
  if ((threadIdx.x&63)==0) ws[threadIdx.x>>6] = v;
  __syncthreads();
  if (threadIdx.x==0){
    int s=0;
    #pragma unroll
    for (int i2=0;i2<SBS/64;i2++) s += ws[i2];
    bsum[blockIdx.x]=s;
  }
}

__global__ __launch_bounds__(SCAN2_T)
void scansum_kernel(const int* __restrict__ bsum, int* __restrict__ boff, int nB)
{
  __shared__ int s[SCAN2_T];
  int t = threadIdx.x;
  int v = (t < nB) ? bsum[t] : 0;
  s[t] = v;
  __syncthreads();
  for (int off=1; off<SCAN2_T; off<<=1){
    int add = (t >= off) ? s[t-off] : 0;
    __syncthreads();
    s[t] += add;
    __syncthreads();
  }
  if (t < nB) boff[t] = (t==0) ? 0 : s[t-1];
}

__global__ __launch_bounds__(SBS)
void blockscan_kernel(const int* __restrict__ deg, const int* __restrict__ boff,
                      int* __restrict__ rowptr, int* __restrict__ cursor, int nN)
{
  __shared__ int s[SBS];
  int t = threadIdx.x;
  int i = blockIdx.x*SBS + t;
  int v = (i < nN) ? deg[i] : 0;
  s[t] = v;
  __syncthreads();
  for (int off=1; off<SBS; off<<=1){
    int add = (t >= off) ? s[t-off] : 0;
    __syncthreads();
    s[t] += add;
    __syncthreads();
  }
  int excl = boff[blockIdx.x] + ((t==0) ? 0 : s[t-1]);
  if (i < nN){ rowptr[i] = excl; cursor[i] = excl; }
  if (i == nN-1) rowptr[nN] = excl + v;
}

__global__ __launch_bounds__(256)
void scatter_kernel(const int* __restrict__ ei, int* __restrict__ cursor,
                    int* __restrict__ csr, int nE)
{
  int e = blockIdx.x*256 + threadIdx.x;
  if (e < nE){
    int s = ei[e], d = ei[nE + e];
    int pos = atomicAdd(&cursor[d], 1);
    csr[pos] = s;
  }
}

// ---- gather: single pass — unnormalized Σexp(e)·h and Σexp(e) ----
__global__ __launch_bounds__(256)
void gather_kernel(const int* __restrict__ rowptr, const int* __restrict__ csr,
                   const float* __restrict__ a_s, const float* __restrict__ a_d,
                   const unsigned short* __restrict__ h_bf,
                   unsigned short* __restrict__ hagg, int nN)
{
  int wave = threadIdx.x >> 6, lane = threadIdx.x & 63;
  int n = blockIdx.x*4 + wave;
  if (n >= nN) return;

  int ro  = rowptr[n];
  int deg = rowptr[n+1] - ro;
  int degT = deg + 1;                       // + self loop
  float ad0 = a_d[(size_t)n*3+0], ad1 = a_d[(size_t)n*3+1], ad2 = a_d[(size_t)n*3+2];

  float d0=0.f, d1=0.f, d2=0.f;
  float acc00=0.f, acc01=0.f, acc10=0.f, acc11=0.f, acc20=0.f, acc21=0.f;

  for (int base=0; base<degT; base+=64){
    int i = base + lane;
    int sReg = n; float p0=0.f, p1=0.f, p2=0.f;
    if (i < degT){
      int s = (i < deg) ? csr[ro+i] : n;
      sReg = s;
      float e0 = a_s[(size_t)s*3+0] + ad0; e0 = e0>0.f ? e0 : NEG*e0;
      float e1 = a_s[(size_t)s*3+1] + ad1; e1 = e1>0.f ? e1 : NEG*e1;
      float e2 = a_s[(size_t)s*3+2] + ad2; e2 = e2>0.f ? e2 : NEG*e2;
      p0 = __expf(e0); p1 = __expf(e1); p2 = __expf(e2);
      d0 += p0; d1 += p1; d2 += p2;
    }
    int cnt = min(64, degT - base);
    for (int j=0;j<cnt;j++){
      int   s  = __shfl(sReg, j);
      float A0 = __shfl(p0, j);
      float A1 = __shfl(p1, j);
      float A2 = __shfl(p2, j);
      ushort2 hv = *(const ushort2*)(h_bf + (size_t)s*128 + 2*lane);
      float f0 = bf2f(hv.x), f1 = bf2f(hv.y);
      acc00 += A0*f0; acc01 += A0*f1;
      acc10 += A1*f0; acc11 += A1*f1;
      acc20 += A2*f0; acc21 += A2*f1;
    }
  }
  #pragma unroll
  for (int off=1; off<64; off<<=1){
    d0 += __shfl_xor(d0, off);
    d1 += __shfl_xor(d1, off);
    d2 += __shfl_xor(d2, off);
  }
  float w0 = 1.f/(d0+1e-16f);
  float w1 = 1.f/(d1+1e-16f);
  float w2 = 1.f/(d2+1e-16f);

  size_t base = (size_t)n*384 + 2*lane;
  ushort2 o0 = {f2bf(acc00*w0), f2bf(acc01*w0)};
  ushort2 o1 = {f2bf(acc10*w1), f2bf(acc11*w1)};
  ushort2 o2 = {f2bf(acc20*w2), f2bf(acc21*w2)};
  *(ushort2*)(hagg + base      ) = o0;
  *(ushort2*)(hagg + base + 128) = o1;
  *(ushort2*)(hagg + base + 256) = o2;
}

// ---- gemm2 v2: LDS-staged B, double-buffered, software-pipelined ----
// out = ((hagg @ B^T) + bias + h) @ out_w + out_b
__global__ __launch_bounds__(256)
void gemm2_kernel(const unsigned short* __restrict__ hagg,
                  const unsigned short* __restrict__ Bt2,
                  const unsigned short* __restrict__ h_bf,
                  const float* __restrict__ gat_bias,
                  const float* __restrict__ out_w, const float* __restrict__ out_b,
                  float* __restrict__ out, int nN)
{
  __shared__ __align__(16) unsigned short Bs[2][128*PADK];
  int tid  = threadIdx.x;
  int wave = tid >> 6, lane = tid & 63;
  int cl = lane & 15, kg = lane >> 4;
  int r0 = blockIdx.x*64 + wave*16;
  int rowA = min(r0 + cl, nN-1);
  const unsigned short* aBase = hagg + (size_t)rowA*384 + kg*8;

  // staging geometry: thread t handles col = t>>1, half = t&1 (16 ushorts = 2 int4)
  int scol = tid >> 1, shalf = tid & 1;
  int dstI = scol*(PADK/8) + shalf*2;        // int4 index into Bs slice (PADK=56 -> 7 int4/col)

  // prologue: stage slice 0
  {
    const int4* src = (const int4*)Bt2;
    int4 t0 = src[2*tid], t1 = src[2*tid+1];
    ((int4*)Bs[0])[dstI]   = t0;
    ((int4*)Bs[0])[dstI+1] = t1;
  }
  f32x4 acc[8];
  #pragma unroll
  for (int f=0;f<8;f++) acc[f] = (f32x4){0.f,0.f,0.f,0.f};
  bf16x8 aCur = *(const bf16x8*)(aBase);
  __syncthreads();

  #pragma unroll
  for (int ks=0; ks<12; ks++){
    int4 t0, t1; bf16x8 aNext;
    if (ks < 11){
      const int4* src = (const int4*)(Bt2 + (size_t)(ks+1)*4096);
      t0 = src[2*tid]; t1 = src[2*tid+1];
      aNext = *(const bf16x8*)(aBase + (ks+1)*32);
    }
    const unsigned short* bs = Bs[ks & 1];
    #pragma unroll
    for (int f=0;f<8;f++){
      bf16x8 b = *(const bf16x8*)(bs + (f*16 + cl)*PADK + kg*8);
      acc[f] = __builtin_amdgcn_mfma_f32_16x16x32_bf16(aCur, b, acc[f], 0, 0, 0);
    }
    if (ks < 11){
      int4* dst = (int4*)Bs[(ks+1) & 1];
      dst[dstI]   = t0;
      dst[dstI+1] = t1;
      aCur = aNext;
    }
    __syncthreads();
  }

  // epilogue: x_new = acc + gat_bias + h ; p = x_new @ out_w ; reduce over cols
  float p[4][4];
  #pragma unroll
  for (int r=0;r<4;r++)
    #pragma unroll
    for (int j=0;j<4;j++) p[r][j]=0.f;

  #pragma unroll
  for (int f=0;f<8;f++){
    int col = f*16 + cl;
    float bias = gat_bias[col];
    float w0=out_w[col*4+0], w1=out_w[col*4+1], w2=out_w[col*4+2], w3=out_w[col*4+3];
    #pragma unroll
    for (int r=0;r<4;r++){
      int row = r0 + kg*4 + r;
      float hres = (row < nN) ? bf2f(h_bf[(size_t)row*128 + col]) : 0.f;
      float xn = acc[f][r] + bias + hres;
      p[r][0] += xn*w0; p[r][1] += xn*w1; p[r][2] += xn*w2; p[r][3] += xn*w3;
    }
  }
  #pragma unroll
  for (int off=1; off<16; off<<=1){
    #pragma unroll
    for (int r=0;r<4;r++)
      #pragma unroll
      for (int j=0;j<4;j++) p[r][j] += __shfl_xor(p[r][j], off);
  }
  if (cl == 0){
    #pragma unroll
    for (int r=0;r<4;r++){
      int row = r0 + kg*4 + r;
      if (row < nN){
        float4 o = {p[r][0]+out_b[0], p[r][1]+out_b[1], p[r][2]+out_b[2], p[r][3]+out_b[3]};
        *(float4*)(out + (size_t)row*4) = o;
      }
    }
  }
}

extern "C" void kernel_launch(void* const* d_in, const int* in_sizes, int n_in,
                              void* d_out, int out_size, void* d_ws, size_t ws_size,
                              hipStream_t stream) {
  const float* x       = (const float*)d_in[0];
  const float* emb_w   = (const float*)d_in[1];
  const float* emb_b   = (const float*)d_in[2];
  const float* gat_w   = (const float*)d_in[3];
  const float* att_src = (const float*)d_in[4];
  const float* att_dst = (const float*)d_in[5];
  const float* gat_bias= (const float*)d_in[6];
  const float* out_w   = (const float*)d_in[7];
  const float* out_b   = (const float*)d_in[8];
  const int*   ei      = (const int*)d_in[9];
  float* out = (float*)d_out;

  int nN = in_sizes[0]/9;
  int nE = in_sizes[9]/2;
  int nB = (nN + SBS - 1) / SBS;

  char* p = (char*)d_ws;
  auto alloc = [&](size_t bytes)->char*{
    char* r = p; p += (bytes + 255) & ~(size_t)255; return r;
  };
  unsigned short* h_bf   = (unsigned short*)alloc((size_t)nN*128*2);
  float*          a_s    = (float*)         alloc((size_t)nN*3*4);
  float*          a_d    = (float*)         alloc((size_t)nN*3*4);
  float*          w_att_s= (float*)         alloc(384*4);
  float*          w_att_d= (float*)         alloc(384*4);
  unsigned short* Bt2    = (unsigned short*)alloc((size_t)12*128*32*2);
  int*            deg    = (int*)           alloc((size_t)nN*4);
  int*            rowptr = (int*)           alloc(((size_t)nN+1)*4);
  int*            cursor = (int*)           alloc((size_t)nN*4);
  int*            csr    = (int*)           alloc((size_t)nE*4);
  int*            bsum   = (int*)           alloc((size_t)nB*4);
  int*            boff   = (int*)           alloc((size_t)nB*4);
  unsigned short* hagg   = (unsigned short*)alloc((size_t)nN*384*2);

  hipMemsetAsync(deg, 0, (size_t)nN*4, stream);

  watt_kernel<<<192, 256, 0, stream>>>(gat_w, att_src, att_dst, w_att_s, w_att_d);
  bt_kernel<<<(12*128*32+255)/256, 256, 0, stream>>>(gat_w, Bt2);

  embed_kernel<<<(nN+NB-1)/NB, 128, 0, stream>>>(
      x, emb_w, emb_b, w_att_s, w_att_d, h_bf, a_s, a_d, nN);

  deg_kernel<<<(nE+255)/256, 256, 0, stream>>>(ei, deg, nE);
  blocksum_kernel<<<nB, SBS, 0, stream>>>(deg, bsum, nN);
  scansum_kernel<<<1, SCAN2_T, 0, stream>>>(bsum, boff, nB);
  blockscan_kernel<<<nB, SBS, 0, stream>>>(deg, boff, rowptr, cursor, nN);
  scatter_kernel<<<(nE+255)/256, 256, 0, stream>>>(ei, cursor, csr, nE);

  gather_kernel<<<(nN+3)/4, 256, 0, stream>>>(
      rowptr, csr, a_s, a_d, h_bf, hagg, nN);

  gemm2_kernel<<<(nN+63)/64, 256, 0, stream>>>(
      hagg, Bt2, h_bf, gat_bias, out_w, out_b, out, nN);
}

// Round 6
// 226.637 us; speedup vs baseline: 2.2924x; 1.0844x over previous
//
#include <hip/hip_runtime.h>
#include <hip/hip_bf16.h>
#include <cstdint>

#define NEG 0.2f
#define SBS 256        // scan block size
#define SCAN2_T 1024   // block-sum scan width
#define PADK 56        // LDS col stride (ushorts): 112B, 16B-aligned, conflict-free

typedef __attribute__((ext_vector_type(8))) short bf16x8;
typedef __attribute__((ext_vector_type(4))) float f32x4;

__device__ __forceinline__ float bf2f(unsigned short u){
  return __uint_as_float(((unsigned)u)<<16);
}
__device__ __forceinline__ unsigned short f2bf(float f){
  __hip_bfloat16 b = __float2bfloat16(f);   // RNE
  return *reinterpret_cast<unsigned short*>(&b);
}

// ---- prep (merged): blocks 0..191 -> w_att ; blocks 192..383 -> Bt2 ----
__global__ __launch_bounds__(256)
void prep_kernel(const float* __restrict__ gat_w, const float* __restrict__ att_src,
                 const float* __restrict__ att_dst, float* __restrict__ w_att_s,
                 float* __restrict__ w_att_d, unsigned short* __restrict__ Bt2)
{
  if (blockIdx.x < 192){
    int wave = threadIdx.x >> 6, lane = threadIdx.x & 63;
    int o = blockIdx.x*4 + wave;          // 0..767
    if (o >= 768) return;
    int isD = (o >= 384);
    int t = isD ? (o - 384) : o;          // h*128 + k
    int h = t >> 7, k = t & 127;
    const float* att = isD ? att_dst : att_src;
    int c = 2*lane;
    float g0 = gat_w[(size_t)k*384 + h*128 + c];
    float g1 = gat_w[(size_t)k*384 + h*128 + c + 1];
    float dot = g0*att[h*128+c] + g1*att[h*128+c+1];
    #pragma unroll
    for (int off=32; off; off>>=1) dot += __shfl_down(dot, off);
    if (lane==0){
      if (isD) w_att_d[t] = dot; else w_att_s[t] = dot;
    }
  } else {
    int i = (blockIdx.x-192)*256 + threadIdx.x;   // 0..49151
    if (i >= 12*128*32) return;
    int ks  = i >> 12;
    int rem = i & 4095;
    int col = rem >> 5;
    int kk  = rem & 31;
    int t = ks*32 + kk;            // 0..383 = h*128 + k
    int h = t >> 7, k = t & 127;
    Bt2[i] = f2bf(gat_w[(size_t)k*384 + h*128 + col] * (1.f/3.f));
  }
}

// ---- embed v2: thread-per-node, zero shuffles ----
__global__ __launch_bounds__(256)
void embed_kernel(const float* __restrict__ x, const float* __restrict__ emb_w,
                  const float* __restrict__ emb_b, const float* __restrict__ w_att_s,
                  const float* __restrict__ w_att_d,
                  unsigned short* __restrict__ h_bf, float* __restrict__ a_s,
                  float* __restrict__ a_d, int nN)
{
  int n = blockIdx.x*256 + threadIdx.x;
  if (n >= nN) return;

  float xv[9];
  #pragma unroll
  for (int k=0;k<9;k++) xv[k] = x[(size_t)n*9 + k];

  float s0=0.f,s1=0.f,s2=0.f, d0=0.f,d1=0.f,d2=0.f;
  unsigned short* hrow = h_bf + (size_t)n*128;

  #pragma unroll 4
  for (int c0=0; c0<128; c0+=8){
    unsigned short pk[8];
    #pragma unroll
    for (int j=0;j<8;j++){
      int c = c0 + j;
      float acc = emb_b[c];
      #pragma unroll
      for (int k=0;k<9;k++) acc += xv[k]*emb_w[k*128+c];
      pk[j] = f2bf(acc);
      s0 += acc*w_att_s[c]; s1 += acc*w_att_s[128+c]; s2 += acc*w_att_s[256+c];
      d0 += acc*w_att_d[c]; d1 += acc*w_att_d[128+c]; d2 += acc*w_att_d[256+c];
    }
    *(int4*)(hrow + c0) = *(int4*)pk;
  }
  a_s[(size_t)n*3+0]=s0; a_s[(size_t)n*3+1]=s1; a_s[(size_t)n*3+2]=s2;
  a_d[(size_t)n*3+0]=d0; a_d[(size_t)n*3+1]=d1; a_d[(size_t)n*3+2]=d2;
}

// ---- CSR build ----
__global__ __launch_bounds__(256)
void deg_kernel(const int* __restrict__ ei, int* __restrict__ deg, int nE)
{
  int e = blockIdx.x*256 + threadIdx.x;
  if (e < nE) atomicAdd(&deg[ei[nE + e]], 1);
}

__global__ __launch_bounds__(SBS)
void blocksum_kernel(const int* __restrict__ deg, int* __restrict__ bsum, int nN)
{
  int i = blockIdx.x*SBS + threadIdx.x;
  int v = (i < nN) ? deg[i] : 0;
  #pragma unroll
  for (int off=32; off; off>>=1) v += __shfl_down(v, off);
  __shared__ int ws[SBS/64];
  if ((threadIdx.x&63)==0) ws[threadIdx.x>>6] = v;
  __syncthreads();
  if (threadIdx.x==0){
    int s=0;
    #pragma unroll
    for (int i2=0;i2<SBS/64;i2++) s += ws[i2];
    bsum[blockIdx.x]=s;
  }
}

__global__ __launch_bounds__(SCAN2_T)
void scansum_kernel(const int* __restrict__ bsum, int* __restrict__ boff, int nB)
{
  __shared__ int s[SCAN2_T];
  int t = threadIdx.x;
  int v = (t < nB) ? bsum[t] : 0;
  s[t] = v;
  __syncthreads();
  for (int off=1; off<SCAN2_T; off<<=1){
    int add = (t >= off) ? s[t-off] : 0;
    __syncthreads();
    s[t] += add;
    __syncthreads();
  }
  if (t < nB) boff[t] = (t==0) ? 0 : s[t-1];
}

__global__ __launch_bounds__(SBS)
void blockscan_kernel(const int* __restrict__ deg, const int* __restrict__ boff,
                      int* __restrict__ rowptr, int* __restrict__ cursor, int nN)
{
  __shared__ int s[SBS];
  int t = threadIdx.x;
  int i = blockIdx.x*SBS + t;
  int v = (i < nN) ? deg[i] : 0;
  s[t] = v;
  __syncthreads();
  for (int off=1; off<SBS; off<<=1){
    int add = (t >= off) ? s[t-off] : 0;
    __syncthreads();
    s[t] += add;
    __syncthreads();
  }
  int excl = boff[blockIdx.x] + ((t==0) ? 0 : s[t-1]);
  if (i < nN){ rowptr[i] = excl; cursor[i] = excl; }
  if (i == nN-1) rowptr[nN] = excl + v;
}

__global__ __launch_bounds__(256)
void scatter_kernel(const int* __restrict__ ei, int* __restrict__ cursor,
                    int* __restrict__ csr, int nE)
{
  int e = blockIdx.x*256 + threadIdx.x;
  if (e < nE){
    int s = ei[e], d = ei[nE + e];
    int pos = atomicAdd(&cursor[d], 1);
    csr[pos] = s;
  }
}

// ---- gather: single pass — unnormalized Σexp(e)·h and Σexp(e) ----
__global__ __launch_bounds__(256)
void gather_kernel(const int* __restrict__ rowptr, const int* __restrict__ csr,
                   const float* __restrict__ a_s, const float* __restrict__ a_d,
                   const unsigned short* __restrict__ h_bf,
                   unsigned short* __restrict__ hagg, int nN)
{
  int wave = threadIdx.x >> 6, lane = threadIdx.x & 63;
  int n = blockIdx.x*4 + wave;
  if (n >= nN) return;

  int ro  = rowptr[n];
  int deg = rowptr[n+1] - ro;
  int degT = deg + 1;                       // + self loop
  float ad0 = a_d[(size_t)n*3+0], ad1 = a_d[(size_t)n*3+1], ad2 = a_d[(size_t)n*3+2];

  float d0=0.f, d1=0.f, d2=0.f;
  float acc00=0.f, acc01=0.f, acc10=0.f, acc11=0.f, acc20=0.f, acc21=0.f;

  for (int base=0; base<degT; base+=64){
    int i = base + lane;
    int sReg = n; float p0=0.f, p1=0.f, p2=0.f;
    if (i < degT){
      int s = (i < deg) ? csr[ro+i] : n;
      sReg = s;
      float e0 = a_s[(size_t)s*3+0] + ad0; e0 = e0>0.f ? e0 : NEG*e0;
      float e1 = a_s[(size_t)s*3+1] + ad1; e1 = e1>0.f ? e1 : NEG*e1;
      float e2 = a_s[(size_t)s*3+2] + ad2; e2 = e2>0.f ? e2 : NEG*e2;
      p0 = __expf(e0); p1 = __expf(e1); p2 = __expf(e2);
      d0 += p0; d1 += p1; d2 += p2;
    }
    int cnt = min(64, degT - base);
    for (int j=0;j<cnt;j++){
      int   s  = __shfl(sReg, j);
      float A0 = __shfl(p0, j);
      float A1 = __shfl(p1, j);
      float A2 = __shfl(p2, j);
      ushort2 hv = *(const ushort2*)(h_bf + (size_t)s*128 + 2*lane);
      float f0 = bf2f(hv.x), f1 = bf2f(hv.y);
      acc00 += A0*f0; acc01 += A0*f1;
      acc10 += A1*f0; acc11 += A1*f1;
      acc20 += A2*f0; acc21 += A2*f1;
    }
  }
  #pragma unroll
  for (int off=1; off<64; off<<=1){
    d0 += __shfl_xor(d0, off);
    d1 += __shfl_xor(d1, off);
    d2 += __shfl_xor(d2, off);
  }
  float w0 = 1.f/(d0+1e-16f);
  float w1 = 1.f/(d1+1e-16f);
  float w2 = 1.f/(d2+1e-16f);

  size_t base = (size_t)n*384 + 2*lane;
  ushort2 o0 = {f2bf(acc00*w0), f2bf(acc01*w0)};
  ushort2 o1 = {f2bf(acc10*w1), f2bf(acc11*w1)};
  ushort2 o2 = {f2bf(acc20*w2), f2bf(acc21*w2)};
  *(ushort2*)(hagg + base      ) = o0;
  *(ushort2*)(hagg + base + 128) = o1;
  *(ushort2*)(hagg + base + 256) = o2;
}

// ---- gemm2: LDS-staged B, double-buffered, software-pipelined ----
__global__ __launch_bounds__(256)
void gemm2_kernel(const unsigned short* __restrict__ hagg,
                  const unsigned short* __restrict__ Bt2,
                  const unsigned short* __restrict__ h_bf,
                  const float* __restrict__ gat_bias,
                  const float* __restrict__ out_w, const float* __restrict__ out_b,
                  float* __restrict__ out, int nN)
{
  __shared__ __align__(16) unsigned short Bs[2][128*PADK];
  int tid  = threadIdx.x;
  int wave = tid >> 6, lane = tid & 63;
  int cl = lane & 15, kg = lane >> 4;
  int r0 = blockIdx.x*64 + wave*16;
  int rowA = min(r0 + cl, nN-1);
  const unsigned short* aBase = hagg + (size_t)rowA*384 + kg*8;

  int scol = tid >> 1, shalf = tid & 1;
  int dstI = scol*(PADK/8) + shalf*2;

  {
    const int4* src = (const int4*)Bt2;
    int4 t0 = src[2*tid], t1 = src[2*tid+1];
    ((int4*)Bs[0])[dstI]   = t0;
    ((int4*)Bs[0])[dstI+1] = t1;
  }
  f32x4 acc[8];
  #pragma unroll
  for (int f=0;f<8;f++) acc[f] = (f32x4){0.f,0.f,0.f,0.f};
  bf16x8 aCur = *(const bf16x8*)(aBase);
  __syncthreads();

  #pragma unroll
  for (int ks=0; ks<12; ks++){
    int4 t0, t1; bf16x8 aNext;
    if (ks < 11){
      const int4* src = (const int4*)(Bt2 + (size_t)(ks+1)*4096);
      t0 = src[2*tid]; t1 = src[2*tid+1];
      aNext = *(const bf16x8*)(aBase + (ks+1)*32);
    }
    const unsigned short* bs = Bs[ks & 1];
    #pragma unroll
    for (int f=0;f<8;f++){
      bf16x8 b = *(const bf16x8*)(bs + (f*16 + cl)*PADK + kg*8);
      acc[f] = __builtin_amdgcn_mfma_f32_16x16x32_bf16(aCur, b, acc[f], 0, 0, 0);
    }
    if (ks < 11){
      int4* dst = (int4*)Bs[(ks+1) & 1];
      dst[dstI]   = t0;
      dst[dstI+1] = t1;
      aCur = aNext;
    }
    __syncthreads();
  }

  float p[4][4];
  #pragma unroll
  for (int r=0;r<4;r++)
    #pragma unroll
    for (int j=0;j<4;j++) p[r][j]=0.f;

  #pragma unroll
  for (int f=0;f<8;f++){
    int col = f*16 + cl;
    float bias = gat_bias[col];
    float w0=out_w[col*4+0], w1=out_w[col*4+1], w2=out_w[col*4+2], w3=out_w[col*4+3];
    #pragma unroll
    for (int r=0;r<4;r++){
      int row = r0 + kg*4 + r;
      float hres = (row < nN) ? bf2f(h_bf[(size_t)row*128 + col]) : 0.f;
      float xn = acc[f][r] + bias + hres;
      p[r][0] += xn*w0; p[r][1] += xn*w1; p[r][2] += xn*w2; p[r][3] += xn*w3;
    }
  }
  #pragma unroll
  for (int off=1; off<16; off<<=1){
    #pragma unroll
    for (int r=0;r<4;r++)
      #pragma unroll
      for (int j=0;j<4;j++) p[r][j] += __shfl_xor(p[r][j], off);
  }
  if (cl == 0){
    #pragma unroll
    for (int r=0;r<4;r++){
      int row = r0 + kg*4 + r;
      if (row < nN){
        float4 o = {p[r][0]+out_b[0], p[r][1]+out_b[1], p[r][2]+out_b[2], p[r][3]+out_b[3]};
        *(float4*)(out + (size_t)row*4) = o;
      }
    }
  }
}

extern "C" void kernel_launch(void* const* d_in, const int* in_sizes, int n_in,
                              void* d_out, int out_size, void* d_ws, size_t ws_size,
                              hipStream_t stream) {
  const float* x       = (const float*)d_in[0];
  const float* emb_w   = (const float*)d_in[1];
  const float* emb_b   = (const float*)d_in[2];
  const float* gat_w   = (const float*)d_in[3];
  const float* att_src = (const float*)d_in[4];
  const float* att_dst = (const float*)d_in[5];
  const float* gat_bias= (const float*)d_in[6];
  const float* out_w   = (const float*)d_in[7];
  const float* out_b   = (const float*)d_in[8];
  const int*   ei      = (const int*)d_in[9];
  float* out = (float*)d_out;

  int nN = in_sizes[0]/9;
  int nE = in_sizes[9]/2;
  int nB = (nN + SBS - 1) / SBS;

  char* p = (char*)d_ws;
  auto alloc = [&](size_t bytes)->char*{
    char* r = p; p += (bytes + 255) & ~(size_t)255; return r;
  };
  unsigned short* h_bf   = (unsigned short*)alloc((size_t)nN*128*2);
  float*          a_s    = (float*)         alloc((size_t)nN*3*4);
  float*          a_d    = (float*)         alloc((size_t)nN*3*4);
  float*          w_att_s= (float*)         alloc(384*4);
  float*          w_att_d= (float*)         alloc(384*4);
  unsigned short* Bt2    = (unsigned short*)alloc((size_t)12*128*32*2);
  int*            deg    = (int*)           alloc((size_t)nN*4);
  int*            rowptr = (int*)           alloc(((size_t)nN+1)*4);
  int*            cursor = (int*)           alloc((size_t)nN*4);
  int*            csr    = (int*)           alloc((size_t)nE*4);
  int*            bsum   = (int*)           alloc((size_t)nB*4);
  int*            boff   = (int*)           alloc((size_t)nB*4);
  unsigned short* hagg   = (unsigned short*)alloc((size_t)nN*384*2);

  hipMemsetAsync(deg, 0, (size_t)nN*4, stream);

  prep_kernel<<<384, 256, 0, stream>>>(gat_w, att_src, att_dst, w_att_s, w_att_d, Bt2);

  embed_kernel<<<(nN+255)/256, 256, 0, stream>>>(
      x, emb_w, emb_b, w_att_s, w_att_d, h_bf, a_s, a_d, nN);

  deg_kernel<<<(nE+255)/256, 256, 0, stream>>>(ei, deg, nE);
  blocksum_kernel<<<nB, SBS, 0, stream>>>(deg, bsum, nN);
  scansum_kernel<<<1, SCAN2_T, 0, stream>>>(bsum, boff, nB);
  blockscan_kernel<<<nB, SBS, 0, stream>>>(deg, boff, rowptr, cursor, nN);
  scatter_kernel<<<(nE+255)/256, 256, 0, stream>>>(ei, cursor, csr, nE);

  gather_kernel<<<(nN+3)/4, 256, 0, stream>>>(
      rowptr, csr, a_s, a_d, h_bf, hagg, nN);

  gemm2_kernel<<<(nN+63)/64, 256, 0, stream>>>(
      hagg, Bt2, h_bf, gat_bias, out_w, out_b, out, nN);
}

// Round 7
// 210.472 us; speedup vs baseline: 2.4685x; 1.0768x over previous
//
#include <hip/hip_runtime.h>
#include <hip/hip_bf16.h>
#include <cstdint>

#define NEG 0.2f
#define SBS 256        // scan block size
#define SCAN2_T 1024   // block-sum scan width
#define PADK 56        // LDS col stride (ushorts): 112B, 16B-aligned, conflict-free

typedef __attribute__((ext_vector_type(8))) short bf16x8;
typedef __attribute__((ext_vector_type(8))) unsigned short ushort8;
typedef __attribute__((ext_vector_type(4))) float f32x4;

__device__ __forceinline__ float bf2f(unsigned short u){
  return __uint_as_float(((unsigned)u)<<16);
}
__device__ __forceinline__ unsigned short f2bf(float f){
  __hip_bfloat16 b = __float2bfloat16(f);   // RNE
  return *reinterpret_cast<unsigned short*>(&b);
}

// ---- prep (merged): blocks 0..191 -> w_att ; blocks 192..383 -> Bt2 ----
__global__ __launch_bounds__(256)
void prep_kernel(const float* __restrict__ gat_w, const float* __restrict__ att_src,
                 const float* __restrict__ att_dst, float* __restrict__ w_att_s,
                 float* __restrict__ w_att_d, unsigned short* __restrict__ Bt2)
{
  if (blockIdx.x < 192){
    int wave = threadIdx.x >> 6, lane = threadIdx.x & 63;
    int o = blockIdx.x*4 + wave;          // 0..767
    if (o >= 768) return;
    int isD = (o >= 384);
    int t = isD ? (o - 384) : o;          // h*128 + k
    int h = t >> 7, k = t & 127;
    const float* att = isD ? att_dst : att_src;
    int c = 2*lane;
    float g0 = gat_w[(size_t)k*384 + h*128 + c];
    float g1 = gat_w[(size_t)k*384 + h*128 + c + 1];
    float dot = g0*att[h*128+c] + g1*att[h*128+c+1];
    #pragma unroll
    for (int off=32; off; off>>=1) dot += __shfl_down(dot, off);
    if (lane==0){
      if (isD) w_att_d[t] = dot; else w_att_s[t] = dot;
    }
  } else {
    int i = (blockIdx.x-192)*256 + threadIdx.x;   // 0..49151
    if (i >= 12*128*32) return;
    int ks  = i >> 12;
    int rem = i & 4095;
    int col = rem >> 5;
    int kk  = rem & 31;
    int t = ks*32 + kk;            // 0..383 = h*128 + k
    int h = t >> 7, k = t & 127;
    Bt2[i] = f2bf(gat_w[(size_t)k*384 + h*128 + col] * (1.f/3.f));
  }
}

// ---- embed: thread-per-node, zero shuffles (weight loads are scalar) ----
__global__ __launch_bounds__(256)
void embed_kernel(const float* __restrict__ x, const float* __restrict__ emb_w,
                  const float* __restrict__ emb_b, const float* __restrict__ w_att_s,
                  const float* __restrict__ w_att_d,
                  unsigned short* __restrict__ h_bf, float* __restrict__ a_s,
                  float* __restrict__ a_d, int nN)
{
  int n = blockIdx.x*256 + threadIdx.x;
  if (n >= nN) return;

  float xv[9];
  #pragma unroll
  for (int k=0;k<9;k++) xv[k] = x[(size_t)n*9 + k];

  float s0=0.f,s1=0.f,s2=0.f, d0=0.f,d1=0.f,d2=0.f;
  unsigned short* hrow = h_bf + (size_t)n*128;

  #pragma unroll 4
  for (int c0=0; c0<128; c0+=8){
    unsigned short pk[8];
    #pragma unroll
    for (int j=0;j<8;j++){
      int c = c0 + j;
      float acc = emb_b[c];
      #pragma unroll
      for (int k=0;k<9;k++) acc += xv[k]*emb_w[k*128+c];
      pk[j] = f2bf(acc);
      s0 += acc*w_att_s[c]; s1 += acc*w_att_s[128+c]; s2 += acc*w_att_s[256+c];
      d0 += acc*w_att_d[c]; d1 += acc*w_att_d[128+c]; d2 += acc*w_att_d[256+c];
    }
    *(int4*)(hrow + c0) = *(int4*)pk;
  }
  a_s[(size_t)n*3+0]=s0; a_s[(size_t)n*3+1]=s1; a_s[(size_t)n*3+2]=s2;
  a_d[(size_t)n*3+0]=d0; a_d[(size_t)n*3+1]=d1; a_d[(size_t)n*3+2]=d2;
}

// ---- CSR build ----
__global__ __launch_bounds__(256)
void deg_kernel(const int* __restrict__ ei, int* __restrict__ deg, int nE)
{
  int e = blockIdx.x*256 + threadIdx.x;
  if (e < nE) atomicAdd(&deg[ei[nE + e]], 1);
}

__global__ __launch_bounds__(SBS)
void blocksum_kernel(const int* __restrict__ deg, int* __restrict__ bsum, int nN)
{
  int i = blockIdx.x*SBS + threadIdx.x;
  int v = (i < nN) ? deg[i] : 0;
  #pragma unroll
  for (int off=32; off; off>>=1) v += __shfl_down(v, off);
  __shared__ int ws[SBS/64];
  if ((threadIdx.x&63)==0) ws[threadIdx.x>>6] = v;
  __syncthreads();
  if (threadIdx.x==0){
    int s=0;
    #pragma unroll
    for (int i2=0;i2<SBS/64;i2++) s += ws[i2];
    bsum[blockIdx.x]=s;
  }
}

__global__ __launch_bounds__(SCAN2_T)
void scansum_kernel(const int* __restrict__ bsum, int* __restrict__ boff, int nB)
{
  __shared__ int s[SCAN2_T];
  int t = threadIdx.x;
  int v = (t < nB) ? bsum[t] : 0;
  s[t] = v;
  __syncthreads();
  for (int off=1; off<SCAN2_T; off<<=1){
    int add = (t >= off) ? s[t-off] : 0;
    __syncthreads();
    s[t] += add;
    __syncthreads();
  }
  if (t < nB) boff[t] = (t==0) ? 0 : s[t-1];
}

__global__ __launch_bounds__(SBS)
void blockscan_kernel(const int* __restrict__ deg, const int* __restrict__ boff,
                      int* __restrict__ rowptr, int* __restrict__ cursor, int nN)
{
  __shared__ int s[SBS];
  int t = threadIdx.x;
  int i = blockIdx.x*SBS + t;
  int v = (i < nN) ? deg[i] : 0;
  s[t] = v;
  __syncthreads();
  for (int off=1; off<SBS; off<<=1){
    int add = (t >= off) ? s[t-off] : 0;
    __syncthreads();
    s[t] += add;
    __syncthreads();
  }
  int excl = boff[blockIdx.x] + ((t==0) ? 0 : s[t-1]);
  if (i < nN){ rowptr[i] = excl; cursor[i] = excl; }
  if (i == nN-1) rowptr[nN] = excl + v;
}

__global__ __launch_bounds__(256)
void scatter_kernel(const int* __restrict__ ei, int* __restrict__ cursor,
                    int* __restrict__ csr, int nE)
{
  int e = blockIdx.x*256 + threadIdx.x;
  if (e < nE){
    int s = ei[e], d = ei[nE + e];
    int pos = atomicAdd(&cursor[d], 1);
    csr[pos] = s;
  }
}

// ---- gather v3: 4 nodes per wave (16-lane groups), 8 ch/lane, 2x unroll ----
__global__ __launch_bounds__(256)
void gather_kernel(const int* __restrict__ rowptr, const int* __restrict__ csr,
                   const float* __restrict__ a_s, const float* __restrict__ a_d,
                   const unsigned short* __restrict__ h_bf,
                   unsigned short* __restrict__ hagg, int nN)
{
  int wave = threadIdx.x >> 6, lane = threadIdx.x & 63;
  int g   = lane >> 4;          // group within wave
  int lin = lane & 15;          // lane within group
  int gb  = lane & 48;          // group base lane
  int n = blockIdx.x*16 + wave*4 + g;
  int valid = (n < nN);
  int nc = valid ? n : (nN-1);

  int ro  = rowptr[nc];
  int deg = rowptr[nc+1] - ro;
  int degT = valid ? (deg + 1) : 0;       // + self loop

  float ad0 = a_d[(size_t)nc*3+0], ad1 = a_d[(size_t)nc*3+1], ad2 = a_d[(size_t)nc*3+2];

  float acc0[8], acc1[8], acc2[8];
  #pragma unroll
  for (int c=0;c<8;c++){ acc0[c]=0.f; acc1[c]=0.f; acc2[c]=0.f; }
  float d0=0.f, d1=0.f, d2=0.f;

  const unsigned short* hb8 = h_bf + 8*lin;

  for (int base=0; base<degT; base+=16){
    int i = base + lin;
    int sReg = nc; float p0=0.f, p1=0.f, p2=0.f;
    if (i < degT){
      int s = (i < deg) ? csr[ro+i] : nc;
      sReg = s;
      float e0 = a_s[(size_t)s*3+0] + ad0; e0 = e0>0.f ? e0 : NEG*e0;
      float e1 = a_s[(size_t)s*3+1] + ad1; e1 = e1>0.f ? e1 : NEG*e1;
      float e2 = a_s[(size_t)s*3+2] + ad2; e2 = e2>0.f ? e2 : NEG*e2;
      p0 = __expf(e0); p1 = __expf(e1); p2 = __expf(e2);
      d0 += p0; d1 += p1; d2 += p2;
    }
    int cnt = min(16, degT - base);
    int j = 0;
    for (; j+1 < cnt; j += 2){
      int   sA = __shfl(sReg, gb+j);
      int   sB = __shfl(sReg, gb+j+1);
      float A0 = __shfl(p0, gb+j),   A1 = __shfl(p1, gb+j),   A2 = __shfl(p2, gb+j);
      float B0 = __shfl(p0, gb+j+1), B1 = __shfl(p1, gb+j+1), B2 = __shfl(p2, gb+j+1);
      ushort8 ha = *(const ushort8*)(hb8 + (size_t)sA*128);
      ushort8 hb = *(const ushort8*)(hb8 + (size_t)sB*128);
      #pragma unroll
      for (int c=0;c<8;c++){
        float fa = bf2f(ha[c]);
        float fb = bf2f(hb[c]);
        acc0[c] += A0*fa + B0*fb;
        acc1[c] += A1*fa + B1*fb;
        acc2[c] += A2*fa + B2*fb;
      }
    }
    if (j < cnt){
      int   sA = __shfl(sReg, gb+j);
      float A0 = __shfl(p0, gb+j), A1 = __shfl(p1, gb+j), A2 = __shfl(p2, gb+j);
      ushort8 ha = *(const ushort8*)(hb8 + (size_t)sA*128);
      #pragma unroll
      for (int c=0;c<8;c++){
        float fa = bf2f(ha[c]);
        acc0[c] += A0*fa; acc1[c] += A1*fa; acc2[c] += A2*fa;
      }
    }
  }

  // denom reduction within 16-lane group
  #pragma unroll
  for (int off=1; off<16; off<<=1){
    d0 += __shfl_xor(d0, off);
    d1 += __shfl_xor(d1, off);
    d2 += __shfl_xor(d2, off);
  }

  if (valid){
    float w0 = 1.f/(d0+1e-16f);
    float w1 = 1.f/(d1+1e-16f);
    float w2 = 1.f/(d2+1e-16f);
    unsigned short o0[8], o1[8], o2[8];
    #pragma unroll
    for (int c=0;c<8;c++){
      o0[c] = f2bf(acc0[c]*w0);
      o1[c] = f2bf(acc1[c]*w1);
      o2[c] = f2bf(acc2[c]*w2);
    }
    size_t bidx = (size_t)n*384 + 8*lin;
    *(int4*)(hagg + bidx      ) = *(int4*)o0;
    *(int4*)(hagg + bidx + 128) = *(int4*)o1;
    *(int4*)(hagg + bidx + 256) = *(int4*)o2;
  }
}

// ---- gemm2: LDS-staged B, double-buffered, software-pipelined ----
__global__ __launch_bounds__(256)
void gemm2_kernel(const unsigned short* __restrict__ hagg,
                  const unsigned short* __restrict__ Bt2,
                  const unsigned short* __restrict__ h_bf,
                  const float* __restrict__ gat_bias,
                  const float* __restrict__ out_w, const float* __restrict__ out_b,
                  float* __restrict__ out, int nN)
{
  __shared__ __align__(16) unsigned short Bs[2][128*PADK];
  int tid  = threadIdx.x;
  int wave = tid >> 6, lane = tid & 63;
  int cl = lane & 15, kg = lane >> 4;
  int r0 = blockIdx.x*64 + wave*16;
  int rowA = min(r0 + cl, nN-1);
  const unsigned short* aBase = hagg + (size_t)rowA*384 + kg*8;

  int scol = tid >> 1, shalf = tid & 1;
  int dstI = scol*(PADK/8) + shalf*2;

  {
    const int4* src = (const int4*)Bt2;
    int4 t0 = src[2*tid], t1 = src[2*tid+1];
    ((int4*)Bs[0])[dstI]   = t0;
    ((int4*)Bs[0])[dstI+1] = t1;
  }
  f32x4 acc[8];
  #pragma unroll
  for (int f=0;f<8;f++) acc[f] = (f32x4){0.f,0.f,0.f,0.f};
  bf16x8 aCur = *(const bf16x8*)(aBase);
  __syncthreads();

  #pragma unroll
  for (int ks=0; ks<12; ks++){
    int4 t0, t1; bf16x8 aNext;
    if (ks < 11){
      const int4* src = (const int4*)(Bt2 + (size_t)(ks+1)*4096);
      t0 = src[2*tid]; t1 = src[2*tid+1];
      aNext = *(const bf16x8*)(aBase + (ks+1)*32);
    }
    const unsigned short* bs = Bs[ks & 1];
    #pragma unroll
    for (int f=0;f<8;f++){
      bf16x8 b = *(const bf16x8*)(bs + (f*16 + cl)*PADK + kg*8);
      acc[f] = __builtin_amdgcn_mfma_f32_16x16x32_bf16(aCur, b, acc[f], 0, 0, 0);
    }
    if (ks < 11){
      int4* dst = (int4*)Bs[(ks+1) & 1];
      dst[dstI]   = t0;
      dst[dstI+1] = t1;
      aCur = aNext;
    }
    __syncthreads();
  }

  float p[4][4];
  #pragma unroll
  for (int r=0;r<4;r++)
    #pragma unroll
    for (int j=0;j<4;j++) p[r][j]=0.f;

  #pragma unroll
  for (int f=0;f<8;f++){
    int col = f*16 + cl;
    float bias = gat_bias[col];
    float w0=out_w[col*4+0], w1=out_w[col*4+1], w2=out_w[col*4+2], w3=out_w[col*4+3];
    #pragma unroll
    for (int r=0;r<4;r++){
      int row = r0 + kg*4 + r;
      float hres = (row < nN) ? bf2f(h_bf[(size_t)row*128 + col]) : 0.f;
      float xn = acc[f][r] + bias + hres;
      p[r][0] += xn*w0; p[r][1] += xn*w1; p[r][2] += xn*w2; p[r][3] += xn*w3;
    }
  }
  #pragma unroll
  for (int off=1; off<16; off<<=1){
    #pragma unroll
    for (int r=0;r<4;r++)
      #pragma unroll
      for (int j=0;j<4;j++) p[r][j] += __shfl_xor(p[r][j], off);
  }
  if (cl == 0){
    #pragma unroll
    for (int r=0;r<4;r++){
      int row = r0 + kg*4 + r;
      if (row < nN){
        float4 o = {p[r][0]+out_b[0], p[r][1]+out_b[1], p[r][2]+out_b[2], p[r][3]+out_b[3]};
        *(float4*)(out + (size_t)row*4) = o;
      }
    }
  }
}

extern "C" void kernel_launch(void* const* d_in, const int* in_sizes, int n_in,
                              void* d_out, int out_size, void* d_ws, size_t ws_size,
                              hipStream_t stream) {
  const float* x       = (const float*)d_in[0];
  const float* emb_w   = (const float*)d_in[1];
  const float* emb_b   = (const float*)d_in[2];
  const float* gat_w   = (const float*)d_in[3];
  const float* att_src = (const float*)d_in[4];
  const float* att_dst = (const float*)d_in[5];
  const float* gat_bias= (const float*)d_in[6];
  const float* out_w   = (const float*)d_in[7];
  const float* out_b   = (const float*)d_in[8];
  const int*   ei      = (const int*)d_in[9];
  float* out = (float*)d_out;

  int nN = in_sizes[0]/9;
  int nE = in_sizes[9]/2;
  int nB = (nN + SBS - 1) / SBS;

  char* p = (char*)d_ws;
  auto alloc = [&](size_t bytes)->char*{
    char* r = p; p += (bytes + 255) & ~(size_t)255; return r;
  };
  unsigned short* h_bf   = (unsigned short*)alloc((size_t)nN*128*2);
  float*          a_s    = (float*)         alloc((size_t)nN*3*4);
  float*          a_d    = (float*)         alloc((size_t)nN*3*4);
  float*          w_att_s= (float*)         alloc(384*4);
  float*          w_att_d= (float*)         alloc(384*4);
  unsigned short* Bt2    = (unsigned short*)alloc((size_t)12*128*32*2);
  int*            deg    = (int*)           alloc((size_t)nN*4);
  int*            rowptr = (int*)           alloc(((size_t)nN+1)*4);
  int*            cursor = (int*)           alloc((size_t)nN*4);
  int*            csr    = (int*)           alloc((size_t)nE*4);
  int*            bsum   = (int*)           alloc((size_t)nB*4);
  int*            boff   = (int*)           alloc((size_t)nB*4);
  unsigned short* hagg   = (unsigned short*)alloc((size_t)nN*384*2);

  hipMemsetAsync(deg, 0, (size_t)nN*4, stream);

  prep_kernel<<<384, 256, 0, stream>>>(gat_w, att_src, att_dst, w_att_s, w_att_d, Bt2);

  embed_kernel<<<(nN+255)/256, 256, 0, stream>>>(
      x, emb_w, emb_b, w_att_s, w_att_d, h_bf, a_s, a_d, nN);

  deg_kernel<<<(nE+255)/256, 256, 0, stream>>>(ei, deg, nE);
  blocksum_kernel<<<nB, SBS, 0, stream>>>(deg, bsum, nN);
  scansum_kernel<<<1, SCAN2_T, 0, stream>>>(bsum, boff, nB);
  blockscan_kernel<<<nB, SBS, 0, stream>>>(deg, boff, rowptr, cursor, nN);
  scatter_kernel<<<(nE+255)/256, 256, 0, stream>>>(ei, cursor, csr, nE);

  gather_kernel<<<(nN+15)/16, 256, 0, stream>>>(
      rowptr, csr, a_s, a_d, h_bf, hagg, nN);

  gemm2_kernel<<<(nN+63)/64, 256, 0, stream>>>(
      hagg, Bt2, h_bf, gat_bias, out_w, out_b, out, nN);
}